// Round 1
// baseline (1543.415 us; speedup 1.0000x reference)
//
#include <hip/hip_runtime.h>
#include <hip/hip_fp16.h>

#define DM 768
#define DS 12288

typedef float    f32x4 __attribute__((ext_vector_type(4)));
typedef _Float16 f16x4 __attribute__((ext_vector_type(4)));
typedef _Float16 f16x8 __attribute__((ext_vector_type(8)));

typedef const __attribute__((address_space(1))) void* gas_t;
typedef __attribute__((address_space(3))) void* las_t;

// ---------------------------------------------------------------- split fp32 -> hi/lo fp16
__global__ void k_split(const float* __restrict__ src, _Float16* __restrict__ hi,
                        _Float16* __restrict__ lo, int n4, float scale)
{
    int i = blockIdx.x * 256 + threadIdx.x;
    if (i >= n4) return;
    f32x4 v = ((const f32x4*)src)[i];
    f16x4 h, l;
#pragma unroll
    for (int j = 0; j < 4; ++j) {
        float vs = v[j] * scale;
        _Float16 hh = (_Float16)vs;
        h[j] = hh;
        l[j] = (_Float16)(vs - (float)hh);
    }
    ((f16x4*)hi)[i] = h;
    ((f16x4*)lo)[i] = l;
}

// ---------------------------------------------------------------- transpose W_dec [DM][DS] -> [DS][DM]
__global__ void k_transpose(const float* __restrict__ W, float* __restrict__ WT)
{
    __shared__ float tile[32][33];
    int bx = blockIdx.x;            // DS/32
    int by = blockIdx.y;            // DM/32
    int tx = threadIdx.x & 31;
    int ty = threadIdx.x >> 5;      // 0..7
#pragma unroll
    for (int j = 0; j < 4; ++j) {
        int d = by * 32 + ty + j * 8;
        tile[ty + j * 8][tx] = W[(long)d * DS + bx * 32 + tx];
    }
    __syncthreads();
#pragma unroll
    for (int j = 0; j < 4; ++j) {
        int s = bx * 32 + ty + j * 8;
        WT[(long)s * DM + by * 32 + tx] = tile[tx][ty + j * 8];
    }
}

// ---------------------------------------------------------------- encode GEMM (fp16x2, 3 MFMA products)
// C[m][s] = (1/4096) * sum_k x'(m,k) * w'(s,k) + b_enc[s]
__global__ __launch_bounds__(256, 2)
void k_encode(const _Float16* __restrict__ Ah, const _Float16* __restrict__ Al,
              const _Float16* __restrict__ Bh, const _Float16* __restrict__ Bl,
              const float* __restrict__ b_enc, float* __restrict__ C)
{
    __shared__ _Float16 sAh[128 * 64];
    __shared__ _Float16 sAl[128 * 64];
    __shared__ _Float16 sBh[128 * 64];
    __shared__ _Float16 sBl[128 * 64];

    const int t    = threadIdx.x;
    const int lane = t & 63;
    const int wave = t >> 6;
    const int bn   = blockIdx.x;        // DS/128
    const int bm   = blockIdx.y;        // M/128
    const int wm   = (wave & 1) * 64;
    const int wn   = (wave >> 1) * 64;
    const int lm   = lane & 15;
    const int quad = lane >> 4;

    f32x4 acc[4][4] = {};

    for (int kt = 0; kt < DM / 64; ++kt) {
        if (kt) __syncthreads();
        const int kbase = kt * 64;
#pragma unroll
        for (int i = 0; i < 4; ++i) {
            int L = i * 256 + t;
            int r = L >> 3;             // tile row 0..127
            int s = L & 7;              // lds slot
            int g = s ^ (r & 7);        // global slot fetched into lds slot s
            long aoff = (long)(bm * 128 + r) * DM + kbase + g * 8;
            long boff = (long)(bn * 128 + r) * DM + kbase + g * 8;
            __builtin_amdgcn_global_load_lds((gas_t)(Ah + aoff), (las_t)&sAh[L * 8], 16, 0, 0);
            __builtin_amdgcn_global_load_lds((gas_t)(Al + aoff), (las_t)&sAl[L * 8], 16, 0, 0);
            __builtin_amdgcn_global_load_lds((gas_t)(Bh + boff), (las_t)&sBh[L * 8], 16, 0, 0);
            __builtin_amdgcn_global_load_lds((gas_t)(Bl + boff), (las_t)&sBl[L * 8], 16, 0, 0);
        }
        __syncthreads();

#pragma unroll
        for (int kc = 0; kc < 2; ++kc) {
            f16x8 a_h[4], a_l[4], b_h[4], b_l[4];
#pragma unroll
            for (int mt = 0; mt < 4; ++mt) {
                int m = wm + mt * 16 + lm;
                int slot = (kc * 4 + quad) ^ (m & 7);
                a_h[mt] = *(const f16x8*)&sAh[m * 64 + slot * 8];
                a_l[mt] = *(const f16x8*)&sAl[m * 64 + slot * 8];
            }
#pragma unroll
            for (int nt = 0; nt < 4; ++nt) {
                int n = wn + nt * 16 + lm;
                int slot = (kc * 4 + quad) ^ (n & 7);
                b_h[nt] = *(const f16x8*)&sBh[n * 64 + slot * 8];
                b_l[nt] = *(const f16x8*)&sBl[n * 64 + slot * 8];
            }
#pragma unroll
            for (int mt = 0; mt < 4; ++mt)
#pragma unroll
                for (int nt = 0; nt < 4; ++nt) {
                    acc[mt][nt] = __builtin_amdgcn_mfma_f32_16x16x32_f16(a_h[mt], b_h[nt], acc[mt][nt], 0, 0, 0);
                    acc[mt][nt] = __builtin_amdgcn_mfma_f32_16x16x32_f16(a_h[mt], b_l[nt], acc[mt][nt], 0, 0, 0);
                    acc[mt][nt] = __builtin_amdgcn_mfma_f32_16x16x32_f16(a_l[mt], b_h[nt], acc[mt][nt], 0, 0, 0);
                }
        }
    }

    const float inv = 1.0f / 4096.0f;   // undo x*16, w*256 scaling
#pragma unroll
    for (int nt = 0; nt < 4; ++nt) {
        int col = bn * 128 + wn + nt * 16 + lm;
        float bias = b_enc[col];
#pragma unroll
        for (int mt = 0; mt < 4; ++mt) {
            int row0 = bm * 128 + wm + mt * 16 + quad * 4;
#pragma unroll
            for (int r = 0; r < 4; ++r)
                C[(long)(row0 + r) * DS + col] = acc[mt][nt][r] * inv + bias;
        }
    }
}

// ---------------------------------------------------------------- per-row top-k + sparse write + decode
__device__ __forceinline__ unsigned fkey(float f)
{
    unsigned u = __float_as_uint(f);
    return (u & 0x80000000u) ? ~u : (u | 0x80000000u);
}

__global__ __launch_bounds__(256, 2)
void k_topk_decode(float* __restrict__ lat,            // dense latents in sparse region (in/out)
                   float* __restrict__ recon,
                   const float* __restrict__ WdT,      // [DS][DM]
                   const float* __restrict__ b_dec,
                   const int* __restrict__ kptr,
                   const float* __restrict__ x,        // for fp64 refinement
                   const float* __restrict__ W_enc,
                   const float* __restrict__ b_enc)
{
    __shared__ float    vals[DS];           // 48 KB
    __shared__ unsigned hist[4096];         // 16 KB
    __shared__ unsigned coarse[256];
    __shared__ float    win_v[64];
    __shared__ int      win_i[64];
    __shared__ float    cand_v[128];
    __shared__ int      cand_i[128];
    __shared__ float    unc_v[32];
    __shared__ int      unc_i[32];
    __shared__ double   unc_d[32];
    __shared__ int      sh_wc, sh_cc, sh_uc;
    __shared__ unsigned sh_B1, sh_B2;
    __shared__ int      sh_nw1;
    __shared__ float    sh_vk;

    const int  t   = threadIdx.x;
    const long row = blockIdx.x;
    float* rowp = lat + row * (long)DS;
    int kk = *kptr; kk = min(max(kk, 1), 64);

#pragma unroll
    for (int j = 0; j < DS / 1024; ++j)
        ((f32x4*)vals)[j * 256 + t] = ((const f32x4*)rowp)[j * 256 + t];

    // ---- level-1 histogram on key[31:20]
    for (int j = t; j < 4096; j += 256) hist[j] = 0;
    __syncthreads();
    for (int j = t; j < DS; j += 256) atomicAdd(&hist[fkey(vals[j]) >> 20], 1u);
    __syncthreads();
    { unsigned c = 0; for (int j = 0; j < 16; ++j) c += hist[t * 16 + j]; coarse[t] = c; }
    __syncthreads();
    if (t == 0) {
        unsigned cum = 0; int b1 = 0;
        for (int c = 255; c >= 0; --c) {
            if (cum + coarse[c] >= (unsigned)kk) {
                for (int b = c * 16 + 15;; --b) {
                    if (cum + hist[b] >= (unsigned)kk) { b1 = b; break; }
                    cum += hist[b];
                }
                break;
            }
            cum += coarse[c];
        }
        sh_B1 = (unsigned)b1; sh_nw1 = (int)cum;
    }
    __syncthreads();
    const unsigned B1 = sh_B1;
    const int k2 = kk - sh_nw1;

    // ---- level-2 histogram on key[19:8] within bin B1
    for (int j = t; j < 4096; j += 256) hist[j] = 0;
    __syncthreads();
    for (int j = t; j < DS; j += 256) {
        unsigned key = fkey(vals[j]);
        if ((key >> 20) == B1) atomicAdd(&hist[(key >> 8) & 0xFFFu], 1u);
    }
    __syncthreads();
    { unsigned c = 0; for (int j = 0; j < 16; ++j) c += hist[t * 16 + j]; coarse[t] = c; }
    __syncthreads();
    if (t == 0) {
        unsigned cum = 0; int b2 = 0;
        for (int c = 255; c >= 0; --c) {
            if (cum + coarse[c] >= (unsigned)k2) {
                for (int b = c * 16 + 15;; --b) {
                    if (cum + hist[b] >= (unsigned)k2) { b2 = b; break; }
                    cum += hist[b];
                }
                break;
            }
            cum += coarse[c];
        }
        sh_B2 = (unsigned)b2; sh_wc = 0; sh_cc = 0;
    }
    __syncthreads();
    const unsigned B2 = sh_B2;

    // ---- collect sure winners + boundary candidates
    for (int j = t; j < DS; j += 256) {
        unsigned key = fkey(vals[j]);
        unsigned b1k = key >> 20;
        if (b1k > B1) {
            int p = atomicAdd(&sh_wc, 1); win_v[p] = vals[j]; win_i[p] = j;
        } else if (b1k == B1) {
            unsigned b2k = (key >> 8) & 0xFFFu;
            if (b2k > B2) {
                int p = atomicAdd(&sh_wc, 1); win_v[p] = vals[j]; win_i[p] = j;
            } else if (b2k == B2) {
                int p = atomicAdd(&sh_cc, 1);
                if (p < 128) { cand_v[p] = vals[j]; cand_i[p] = j; }
            }
        }
    }
    __syncthreads();
    if (t == 0) {
        int nw = sh_wc, m = kk - nw, c = min(sh_cc, 128);
        for (int s = 0; s < m; ++s) {
            unsigned bk = 0; int bj = -1, bi = 0x7fffffff;
            for (int j = 0; j < c; ++j) {
                unsigned kj = fkey(cand_v[j]);
                if (bj < 0 || kj > bk || (kj == bk && cand_i[j] < bi)) { bj = j; bk = kj; bi = cand_i[j]; }
            }
            win_v[nw + s] = cand_v[bj]; win_i[nw + s] = cand_i[bj];
            cand_v[bj] = -3.0e38f; cand_i[bj] = 0x7fffffff;
        }
        float vk = win_v[0];
        for (int i = 1; i < kk; ++i) vk = fminf(vk, win_v[i]);
        sh_vk = vk; sh_uc = 0;
    }
    __syncthreads();

    // ---- fp64 refinement of near-boundary ties (selection must match fp64 reference)
    const float vk = sh_vk;
    const float EPS = 1e-3f;
    for (int j = t; j < DS; j += 256) {
        float v = vals[j];
        if (fabsf(v - vk) <= EPS) {
            int p = atomicAdd(&sh_uc, 1);
            if (p < 32) { unc_v[p] = v; unc_i[p] = j; }
        }
    }
    __syncthreads();
    const int un = sh_uc;
    if (un > 1 && un <= 32) {
        const int wv = t >> 6, ln = t & 63;
        const float* xr = x + row * DM;
        for (int e = wv; e < un; e += 4) {
            const float* wr = W_enc + (long)unc_i[e] * DM;
            double s = 0.0;
            for (int d = ln; d < DM; d += 64) s += (double)xr[d] * (double)wr[d];
#pragma unroll
            for (int off = 32; off; off >>= 1) s += __shfl_down(s, off);
            if (ln == 0) unc_d[e] = s + (double)b_enc[unc_i[e]];
        }
        __syncthreads();
        if (t == 0) {
            int a = 0;
            for (int i = 0; i < kk; ++i)
                if (win_v[i] > vk + EPS) { win_v[a] = win_v[i]; win_i[a] = win_i[i]; ++a; }
            int need = kk - a;
            for (int s = 0; s < need; ++s) {
                int bj = -1, bi = 0x7fffffff; double bd = 0.0;
                for (int j = 0; j < un; ++j) {
                    if (unc_i[j] < 0) continue;
                    double dj = unc_d[j];
                    if (bj < 0 || dj > bd || (dj == bd && unc_i[j] < bi)) { bj = j; bd = dj; bi = unc_i[j]; }
                }
                win_v[a + s] = unc_v[bj]; win_i[a + s] = unc_i[bj];
                unc_i[bj] = -1;
            }
        }
        __syncthreads();
    }

    // ---- rewrite sparse row: zeros + scatter top-k
    f32x4 z = {0.f, 0.f, 0.f, 0.f};
#pragma unroll
    for (int j = 0; j < DS / 1024; ++j)
        ((f32x4*)rowp)[j * 256 + t] = z;
    __syncthreads();
    if (t < kk) rowp[win_i[t]] = win_v[t];

    // ---- decode: recon[row][d] = b_dec[d] + sum_i v_i * WdT[s_i][d]
    float a0 = b_dec[t], a1 = b_dec[t + 256], a2 = b_dec[t + 512];
    for (int i = 0; i < kk; ++i) {
        float v = win_v[i];
        const float* w = WdT + (long)win_i[i] * DM;
        a0 += v * w[t];
        a1 += v * w[t + 256];
        a2 += v * w[t + 512];
    }
    float* rr = recon + row * DM;
    rr[t] = a0; rr[t + 256] = a1; rr[t + 512] = a2;
}

// ---------------------------------------------------------------- launch
extern "C" void kernel_launch(void* const* d_in, const int* in_sizes, int n_in,
                              void* d_out, int out_size, void* d_ws, size_t ws_size,
                              hipStream_t stream)
{
    const float* x     = (const float*)d_in[0];
    const float* W_enc = (const float*)d_in[1];
    const float* b_enc = (const float*)d_in[2];
    const float* W_dec = (const float*)d_in[3];
    const float* b_dec = (const float*)d_in[4];
    const int*   kptr  = (const int*)d_in[5];

    const int dmodel = in_sizes[4];               // 768
    const int dsae   = in_sizes[2];               // 12288
    const int M      = in_sizes[0] / dmodel;      // 8192

    float* recon  = (float*)d_out;                          // [M][DM]
    float* sparse = (float*)d_out + (size_t)M * dmodel;     // [M][DS] (also dense-latent scratch)

    char* ws = (char*)d_ws;
    _Float16* xh = (_Float16*)ws; ws += (size_t)M * dmodel * 2;
    _Float16* xl = (_Float16*)ws; ws += (size_t)M * dmodel * 2;
    _Float16* wh = (_Float16*)ws; ws += (size_t)dsae * dmodel * 2;
    _Float16* wl = (_Float16*)ws; ws += (size_t)dsae * dmodel * 2;
    float*   WdT = (float*)ws;    ws += (size_t)dsae * dmodel * 4;

    const int n4x = M * dmodel / 4;
    const int n4w = dsae * dmodel / 4;
    k_split<<<(n4x + 255) / 256, 256, 0, stream>>>(x, xh, xl, n4x, 16.0f);
    k_split<<<(n4w + 255) / 256, 256, 0, stream>>>(W_enc, wh, wl, n4w, 256.0f);
    k_transpose<<<dim3(dsae / 32, dmodel / 32), 256, 0, stream>>>(W_dec, WdT);
    k_encode<<<dim3(dsae / 128, M / 128), 256, 0, stream>>>(xh, xl, wh, wl, b_enc, sparse);
    k_topk_decode<<<M, 256, 0, stream>>>(sparse, recon, WdT, b_dec, kptr, x, W_enc, b_enc);
}

// Round 2
// 1377.142 us; speedup vs baseline: 1.1207x; 1.1207x over previous
//
#include <hip/hip_runtime.h>
#include <hip/hip_fp16.h>

#define DM 768
#define DS 12288

typedef float    f32x4 __attribute__((ext_vector_type(4)));
typedef _Float16 f16x4 __attribute__((ext_vector_type(4)));
typedef _Float16 f16x8 __attribute__((ext_vector_type(8)));

typedef const __attribute__((address_space(1))) void* gas_t;
typedef __attribute__((address_space(3))) void* las_t;

// ---------------------------------------------------------------- split fp32 -> hi/lo fp16
__global__ void k_split(const float* __restrict__ src, _Float16* __restrict__ hi,
                        _Float16* __restrict__ lo, int n4, float scale)
{
    int i = blockIdx.x * 256 + threadIdx.x;
    if (i >= n4) return;
    f32x4 v = ((const f32x4*)src)[i];
    f16x4 h, l;
#pragma unroll
    for (int j = 0; j < 4; ++j) {
        float vs = v[j] * scale;
        _Float16 hh = (_Float16)vs;
        h[j] = hh;
        l[j] = (_Float16)(vs - (float)hh);
    }
    ((f16x4*)hi)[i] = h;
    ((f16x4*)lo)[i] = l;
}

// ---------------------------------------------------------------- transpose W_dec [DM][DS] -> [DS][DM]
__global__ void k_transpose(const float* __restrict__ W, float* __restrict__ WT)
{
    __shared__ float tile[32][33];
    int bx = blockIdx.x;            // DS/32
    int by = blockIdx.y;            // DM/32
    int tx = threadIdx.x & 31;
    int ty = threadIdx.x >> 5;      // 0..7
#pragma unroll
    for (int j = 0; j < 4; ++j) {
        int d = by * 32 + ty + j * 8;
        tile[ty + j * 8][tx] = W[(long)d * DS + bx * 32 + tx];
    }
    __syncthreads();
#pragma unroll
    for (int j = 0; j < 4; ++j) {
        int s = bx * 32 + ty + j * 8;
        WT[(long)s * DM + by * 32 + tx] = tile[tx][ty + j * 8];
    }
}

// ---------------------------------------------------------------- encode GEMM (fp16x2, 3 MFMA products)
__global__ __launch_bounds__(256, 2)
void k_encode(const _Float16* __restrict__ Ah, const _Float16* __restrict__ Al,
              const _Float16* __restrict__ Bh, const _Float16* __restrict__ Bl,
              const float* __restrict__ b_enc, float* __restrict__ C)
{
    __shared__ _Float16 sAh[128 * 64];
    __shared__ _Float16 sAl[128 * 64];
    __shared__ _Float16 sBh[128 * 64];
    __shared__ _Float16 sBl[128 * 64];

    const int t    = threadIdx.x;
    const int lane = t & 63;
    const int wave = t >> 6;
    const int bn   = blockIdx.x;        // DS/128
    const int bm   = blockIdx.y;        // M/128
    const int wm   = (wave & 1) * 64;
    const int wn   = (wave >> 1) * 64;
    const int lm   = lane & 15;
    const int quad = lane >> 4;

    f32x4 acc[4][4] = {};

    for (int kt = 0; kt < DM / 64; ++kt) {
        if (kt) __syncthreads();
        const int kbase = kt * 64;
#pragma unroll
        for (int i = 0; i < 4; ++i) {
            int L = i * 256 + t;
            int r = L >> 3;             // tile row 0..127
            int s = L & 7;              // lds slot
            int g = s ^ (r & 7);        // global slot fetched into lds slot s
            long aoff = (long)(bm * 128 + r) * DM + kbase + g * 8;
            long boff = (long)(bn * 128 + r) * DM + kbase + g * 8;
            __builtin_amdgcn_global_load_lds((gas_t)(Ah + aoff), (las_t)&sAh[L * 8], 16, 0, 0);
            __builtin_amdgcn_global_load_lds((gas_t)(Al + aoff), (las_t)&sAl[L * 8], 16, 0, 0);
            __builtin_amdgcn_global_load_lds((gas_t)(Bh + boff), (las_t)&sBh[L * 8], 16, 0, 0);
            __builtin_amdgcn_global_load_lds((gas_t)(Bl + boff), (las_t)&sBl[L * 8], 16, 0, 0);
        }
        __syncthreads();

#pragma unroll
        for (int kc = 0; kc < 2; ++kc) {
            f16x8 a_h[4], a_l[4], b_h[4], b_l[4];
#pragma unroll
            for (int mt = 0; mt < 4; ++mt) {
                int m = wm + mt * 16 + lm;
                int slot = (kc * 4 + quad) ^ (m & 7);
                a_h[mt] = *(const f16x8*)&sAh[m * 64 + slot * 8];
                a_l[mt] = *(const f16x8*)&sAl[m * 64 + slot * 8];
            }
#pragma unroll
            for (int nt = 0; nt < 4; ++nt) {
                int n = wn + nt * 16 + lm;
                int slot = (kc * 4 + quad) ^ (n & 7);
                b_h[nt] = *(const f16x8*)&sBh[n * 64 + slot * 8];
                b_l[nt] = *(const f16x8*)&sBl[n * 64 + slot * 8];
            }
#pragma unroll
            for (int mt = 0; mt < 4; ++mt)
#pragma unroll
                for (int nt = 0; nt < 4; ++nt) {
                    acc[mt][nt] = __builtin_amdgcn_mfma_f32_16x16x32_f16(a_h[mt], b_h[nt], acc[mt][nt], 0, 0, 0);
                    acc[mt][nt] = __builtin_amdgcn_mfma_f32_16x16x32_f16(a_h[mt], b_l[nt], acc[mt][nt], 0, 0, 0);
                    acc[mt][nt] = __builtin_amdgcn_mfma_f32_16x16x32_f16(a_l[mt], b_h[nt], acc[mt][nt], 0, 0, 0);
                }
        }
    }

    const float inv = 1.0f / 4096.0f;   // undo x*16, w*256 scaling
#pragma unroll
    for (int nt = 0; nt < 4; ++nt) {
        int col = bn * 128 + wn + nt * 16 + lm;
        float bias = b_enc[col];
#pragma unroll
        for (int mt = 0; mt < 4; ++mt) {
            int row0 = bm * 128 + wm + mt * 16 + quad * 4;
#pragma unroll
            for (int r = 0; r < 4; ++r)
                C[(long)(row0 + r) * DS + col] = acc[mt][nt][r] * inv + bias;
        }
    }
}

// ---------------------------------------------------------------- per-row top-k selection
__device__ __forceinline__ unsigned fkey(float f)
{
    unsigned u = __float_as_uint(f);
    return (u & 0x80000000u) ? ~u : (u | 0x80000000u);
}

// Row staged in REGISTERS (48 VGPR), one 4096-bin histogram, parallel suffix-scan
// threshold find. Writes (val, idx) pairs only.
__global__ __launch_bounds__(256, 4)
void k_topk(const float* __restrict__ lat, const int* __restrict__ kptr,
            float* __restrict__ owv, int* __restrict__ owi,
            const float* __restrict__ x, const float* __restrict__ W_enc,
            const float* __restrict__ b_enc)
{
    __shared__ unsigned hist[4096];         // 16 KB
    __shared__ unsigned suf[256];           // chunk suffix sums
    __shared__ float    win_v[64];
    __shared__ int      win_i[64];
    __shared__ float    cand_v[256];
    __shared__ int      cand_i[256];
    __shared__ float    unc_v[32];
    __shared__ int      unc_i[32];
    __shared__ double   unc_d[32];
    __shared__ int      sh_wc, sh_cc, sh_uc;
    __shared__ unsigned sh_B1;
    __shared__ float    sh_vk;

    const int  t   = threadIdx.x;
    const long row = blockIdx.x;
    const float* rowp = lat + row * (long)DS;
    int kk = *kptr; kk = min(max(kk, 1), 64);

    // stage the row in registers: element index of v[j][c] = (j*256+t)*4 + c
    f32x4 v[12];
#pragma unroll
    for (int j = 0; j < 12; ++j) v[j] = ((const f32x4*)rowp)[j * 256 + t];

    // ---- 4096-bin histogram on key[31:20]
    for (int j = t; j < 4096; j += 256) hist[j] = 0;
    if (t == 0) { sh_wc = 0; sh_cc = 0; sh_uc = 0; }
    __syncthreads();
#pragma unroll
    for (int j = 0; j < 12; ++j)
#pragma unroll
        for (int c = 0; c < 4; ++c)
            atomicAdd(&hist[fkey(v[j][c]) >> 20], 1u);
    __syncthreads();

    // ---- coarse sums (16 bins/thread) + parallel suffix-scan over 256 chunks
    {
        unsigned csum = 0;
#pragma unroll
        for (int b = 0; b < 16; ++b) csum += hist[t * 16 + b];
        suf[t] = csum;
    }
    __syncthreads();
    for (int off = 1; off < 256; off <<= 1) {
        unsigned add = (t + off < 256) ? suf[t + off] : 0u;
        __syncthreads();
        suf[t] += add;
        __syncthreads();
    }
    // suf[c] = count of elements with chunk index >= c (suffix-sum, monotone nonincreasing)
    {
        unsigned above = (t < 255) ? suf[t + 1] : 0u;
        if (suf[t] >= (unsigned)kk && above < (unsigned)kk) {
            // threshold bin is inside chunk t: walk its 16 bins high->low
            unsigned cum = above;
            for (int b = t * 16 + 15;; --b) {
                if (cum + hist[b] >= (unsigned)kk) { sh_B1 = (unsigned)b; break; }
                cum += hist[b];
            }
        }
    }
    __syncthreads();
    const unsigned B1 = sh_B1;

    // ---- collect sure winners (bin > B1) + boundary candidates (bin == B1) from registers
#pragma unroll
    for (int j = 0; j < 12; ++j)
#pragma unroll
        for (int c = 0; c < 4; ++c) {
            float f = v[j][c];
            unsigned b = fkey(f) >> 20;
            int idx = (j * 256 + t) * 4 + c;
            if (b > B1) {
                int p = atomicAdd(&sh_wc, 1); win_v[p] = f; win_i[p] = idx;
            } else if (b == B1) {
                int p = atomicAdd(&sh_cc, 1);
                if (p < 256) { cand_v[p] = f; cand_i[p] = idx; }
            }
        }
    __syncthreads();
    if (t == 0) {
        int nw = sh_wc, m = kk - nw, cc = min(sh_cc, 256);
        for (int s = 0; s < m; ++s) {
            unsigned bk = 0; int bj = -1, bi = 0x7fffffff;
            for (int j = 0; j < cc; ++j) {
                unsigned kj = fkey(cand_v[j]);
                if (bj < 0 || kj > bk || (kj == bk && cand_i[j] < bi)) { bj = j; bk = kj; bi = cand_i[j]; }
            }
            if (bj < 0) break;
            win_v[nw + s] = cand_v[bj]; win_i[nw + s] = cand_i[bj];
            cand_v[bj] = -3.0e38f; cand_i[bj] = 0x7fffffff;
        }
        float vk = win_v[0];
        for (int i = 1; i < kk; ++i) vk = fminf(vk, win_v[i]);
        sh_vk = vk;
    }
    __syncthreads();

    // ---- fp64 refinement of near-boundary ties (selection must match fp64 reference)
    const float vk = sh_vk;
    const float EPS = 1e-3f;
#pragma unroll
    for (int j = 0; j < 12; ++j)
#pragma unroll
        for (int c = 0; c < 4; ++c) {
            float f = v[j][c];
            if (fabsf(f - vk) <= EPS) {
                int p = atomicAdd(&sh_uc, 1);
                if (p < 32) { unc_v[p] = f; unc_i[p] = (j * 256 + t) * 4 + c; }
            }
        }
    __syncthreads();
    const int un = sh_uc;
    if (un > 1 && un <= 32) {
        const int wv = t >> 6, ln = t & 63;
        const float* xr = x + row * DM;
        for (int e = wv; e < un; e += 4) {
            const float* wr = W_enc + (long)unc_i[e] * DM;
            double s = 0.0;
            for (int d = ln; d < DM; d += 64) s += (double)xr[d] * (double)wr[d];
#pragma unroll
            for (int off = 32; off; off >>= 1) s += __shfl_down(s, off);
            if (ln == 0) unc_d[e] = s + (double)b_enc[unc_i[e]];
        }
        __syncthreads();
        if (t == 0) {
            int a = 0;
            for (int i = 0; i < kk; ++i)
                if (win_v[i] > vk + EPS) { win_v[a] = win_v[i]; win_i[a] = win_i[i]; ++a; }
            int need = kk - a;
            for (int s = 0; s < need; ++s) {
                int bj = -1, bi = 0x7fffffff; double bd = 0.0;
                for (int j = 0; j < un; ++j) {
                    if (unc_i[j] < 0) continue;
                    double dj = unc_d[j];
                    if (bj < 0 || dj > bd || (dj == bd && unc_i[j] < bi)) { bj = j; bd = dj; bi = unc_i[j]; }
                }
                win_v[a + s] = unc_v[bj]; win_i[a + s] = unc_i[bj];
                unc_i[bj] = -1;
            }
        }
        __syncthreads();
    }

    if (t < kk) { owv[row * 64 + t] = win_v[t]; owi[row * 64 + t] = win_i[t]; }
}

// ---------------------------------------------------------------- zero + scatter + decode
__global__ __launch_bounds__(256)
void k_scatter_decode(float* __restrict__ sparse, float* __restrict__ recon,
                      const float* __restrict__ WdT, const float* __restrict__ b_dec,
                      const float* __restrict__ owv, const int* __restrict__ owi,
                      const int* __restrict__ kptr)
{
    __shared__ float sv[64];
    __shared__ int   si[64];
    const int  t   = threadIdx.x;
    const long row = blockIdx.x;
    int kk = *kptr; kk = min(max(kk, 1), 64);

    if (t < kk) { sv[t] = owv[row * 64 + t]; si[t] = owi[row * 64 + t]; }
    float* rowp = sparse + row * (long)DS;
    f32x4 z = {0.f, 0.f, 0.f, 0.f};
#pragma unroll
    for (int j = 0; j < 12; ++j) ((f32x4*)rowp)[j * 256 + t] = z;
    __syncthreads();
    if (t < kk) rowp[si[t]] = sv[t];

    float a0 = b_dec[t], a1 = b_dec[t + 256], a2 = b_dec[t + 512];
    for (int i = 0; i < kk; ++i) {
        float val = sv[i];
        const float* w = WdT + (long)si[i] * DM;
        a0 += val * w[t];
        a1 += val * w[t + 256];
        a2 += val * w[t + 512];
    }
    float* rr = recon + row * DM;
    rr[t] = a0; rr[t + 256] = a1; rr[t + 512] = a2;
}

// ---------------------------------------------------------------- launch
extern "C" void kernel_launch(void* const* d_in, const int* in_sizes, int n_in,
                              void* d_out, int out_size, void* d_ws, size_t ws_size,
                              hipStream_t stream)
{
    const float* x     = (const float*)d_in[0];
    const float* W_enc = (const float*)d_in[1];
    const float* b_enc = (const float*)d_in[2];
    const float* W_dec = (const float*)d_in[3];
    const float* b_dec = (const float*)d_in[4];
    const int*   kptr  = (const int*)d_in[5];

    const int dmodel = in_sizes[4];               // 768
    const int dsae   = in_sizes[2];               // 12288
    const int M      = in_sizes[0] / dmodel;      // 8192

    float* recon  = (float*)d_out;                          // [M][DM]
    float* sparse = (float*)d_out + (size_t)M * dmodel;     // [M][DS] (also dense-latent scratch)

    char* ws = (char*)d_ws;
    _Float16* xh = (_Float16*)ws; ws += (size_t)M * dmodel * 2;
    _Float16* xl = (_Float16*)ws; ws += (size_t)M * dmodel * 2;
    _Float16* wh = (_Float16*)ws; ws += (size_t)dsae * dmodel * 2;
    _Float16* wl = (_Float16*)ws; ws += (size_t)dsae * dmodel * 2;
    float*   WdT = (float*)ws;    ws += (size_t)dsae * dmodel * 4;
    float*   owv = (float*)ws;    ws += (size_t)M * 64 * 4;
    int*     owi = (int*)ws;      ws += (size_t)M * 64 * 4;

    const int n4x = M * dmodel / 4;
    const int n4w = dsae * dmodel / 4;
    k_split<<<(n4x + 255) / 256, 256, 0, stream>>>(x, xh, xl, n4x, 16.0f);
    k_split<<<(n4w + 255) / 256, 256, 0, stream>>>(W_enc, wh, wl, n4w, 256.0f);
    k_transpose<<<dim3(dsae / 32, dmodel / 32), 256, 0, stream>>>(W_dec, WdT);
    k_encode<<<dim3(dsae / 128, M / 128), 256, 0, stream>>>(xh, xl, wh, wl, b_enc, sparse);
    k_topk<<<M, 256, 0, stream>>>(sparse, kptr, owv, owi, x, W_enc, b_enc);
    k_scatter_decode<<<M, 256, 0, stream>>>(sparse, recon, WdT, b_dec, owv, owi, kptr);
}

// Round 3
// 1138.079 us; speedup vs baseline: 1.3562x; 1.2101x over previous
//
#include <hip/hip_runtime.h>
#include <hip/hip_fp16.h>

#define DM 768
#define DS 12288

typedef float    f32x4 __attribute__((ext_vector_type(4)));
typedef _Float16 f16x4 __attribute__((ext_vector_type(4)));
typedef _Float16 f16x8 __attribute__((ext_vector_type(8)));

typedef const __attribute__((address_space(1))) void* gas_t;
typedef __attribute__((address_space(3))) void* las_t;

// ---------------------------------------------------------------- split fp32 -> hi/lo fp16
__global__ void k_split(const float* __restrict__ src, _Float16* __restrict__ hi,
                        _Float16* __restrict__ lo, int n4, float scale)
{
    int i = blockIdx.x * 256 + threadIdx.x;
    if (i >= n4) return;
    f32x4 v = ((const f32x4*)src)[i];
    f16x4 h, l;
#pragma unroll
    for (int j = 0; j < 4; ++j) {
        float vs = v[j] * scale;
        _Float16 hh = (_Float16)vs;
        h[j] = hh;
        l[j] = (_Float16)(vs - (float)hh);
    }
    ((f16x4*)hi)[i] = h;
    ((f16x4*)lo)[i] = l;
}

// hi-only variant (x's lo half is dropped from the GEMM: error ~1e-4, handled by tie refine)
__global__ void k_split1(const float* __restrict__ src, _Float16* __restrict__ hi,
                         int n4, float scale)
{
    int i = blockIdx.x * 256 + threadIdx.x;
    if (i >= n4) return;
    f32x4 v = ((const f32x4*)src)[i];
    f16x4 h;
#pragma unroll
    for (int j = 0; j < 4; ++j) h[j] = (_Float16)(v[j] * scale);
    ((f16x4*)hi)[i] = h;
}

// ---------------------------------------------------------------- transpose W_dec [DM][DS] -> [DS][DM]
__global__ void k_transpose(const float* __restrict__ W, float* __restrict__ WT)
{
    __shared__ float tile[32][33];
    int bx = blockIdx.x;            // DS/32
    int by = blockIdx.y;            // DM/32
    int tx = threadIdx.x & 31;
    int ty = threadIdx.x >> 5;      // 0..7
#pragma unroll
    for (int j = 0; j < 4; ++j) {
        int d = by * 32 + ty + j * 8;
        tile[ty + j * 8][tx] = W[(long)d * DS + bx * 32 + tx];
    }
    __syncthreads();
#pragma unroll
    for (int j = 0; j < 4; ++j) {
        int s = bx * 32 + ty + j * 8;
        WT[(long)s * DM + by * 32 + tx] = tile[tx][ty + j * 8];
    }
}

// ---------------------------------------------------------------- encode GEMM (2 MFMA products: xh*wh + xh*wl)
__global__ __launch_bounds__(256, 3)
void k_encode(const _Float16* __restrict__ Ah,
              const _Float16* __restrict__ Bh, const _Float16* __restrict__ Bl,
              const float* __restrict__ b_enc, float* __restrict__ C)
{
    __shared__ _Float16 sAh[128 * 64];
    __shared__ _Float16 sBh[128 * 64];
    __shared__ _Float16 sBl[128 * 64];

    const int t    = threadIdx.x;
    const int lane = t & 63;
    const int wave = t >> 6;
    const int bn   = blockIdx.x;        // DS/128
    const int bm   = blockIdx.y;        // M/128
    const int wm   = (wave & 1) * 64;
    const int wn   = (wave >> 1) * 64;
    const int lm   = lane & 15;
    const int quad = lane >> 4;

    f32x4 acc[4][4] = {};

    for (int kt = 0; kt < DM / 64; ++kt) {
        if (kt) __syncthreads();
        const int kbase = kt * 64;
#pragma unroll
        for (int i = 0; i < 4; ++i) {
            int L = i * 256 + t;
            int r = L >> 3;             // tile row 0..127
            int s = L & 7;              // lds slot
            int g = s ^ (r & 7);        // global slot fetched into lds slot s
            long aoff = (long)(bm * 128 + r) * DM + kbase + g * 8;
            long boff = (long)(bn * 128 + r) * DM + kbase + g * 8;
            __builtin_amdgcn_global_load_lds((gas_t)(Ah + aoff), (las_t)&sAh[L * 8], 16, 0, 0);
            __builtin_amdgcn_global_load_lds((gas_t)(Bh + boff), (las_t)&sBh[L * 8], 16, 0, 0);
            __builtin_amdgcn_global_load_lds((gas_t)(Bl + boff), (las_t)&sBl[L * 8], 16, 0, 0);
        }
        __syncthreads();

#pragma unroll
        for (int kc = 0; kc < 2; ++kc) {
            f16x8 a_h[4], b_h[4], b_l[4];
#pragma unroll
            for (int mt = 0; mt < 4; ++mt) {
                int m = wm + mt * 16 + lm;
                int slot = (kc * 4 + quad) ^ (m & 7);
                a_h[mt] = *(const f16x8*)&sAh[m * 64 + slot * 8];
            }
#pragma unroll
            for (int nt = 0; nt < 4; ++nt) {
                int n = wn + nt * 16 + lm;
                int slot = (kc * 4 + quad) ^ (n & 7);
                b_h[nt] = *(const f16x8*)&sBh[n * 64 + slot * 8];
                b_l[nt] = *(const f16x8*)&sBl[n * 64 + slot * 8];
            }
#pragma unroll
            for (int mt = 0; mt < 4; ++mt)
#pragma unroll
                for (int nt = 0; nt < 4; ++nt) {
                    acc[mt][nt] = __builtin_amdgcn_mfma_f32_16x16x32_f16(a_h[mt], b_h[nt], acc[mt][nt], 0, 0, 0);
                    acc[mt][nt] = __builtin_amdgcn_mfma_f32_16x16x32_f16(a_h[mt], b_l[nt], acc[mt][nt], 0, 0, 0);
                }
        }
    }

    const float inv = 1.0f / 4096.0f;   // undo x*16, w*256 scaling
#pragma unroll
    for (int nt = 0; nt < 4; ++nt) {
        int col = bn * 128 + wn + nt * 16 + lm;
        float bias = b_enc[col];
#pragma unroll
        for (int mt = 0; mt < 4; ++mt) {
            int row0 = bm * 128 + wm + mt * 16 + quad * 4;
#pragma unroll
            for (int r = 0; r < 4; ++r)
                __builtin_nontemporal_store(acc[mt][nt][r] * inv + bias,
                                            &C[(long)(row0 + r) * DS + col]);
        }
    }
}

// ---------------------------------------------------------------- fused top-k + scatter + decode
__device__ __forceinline__ unsigned fkey(float f)
{
    unsigned u = __float_as_uint(f);
    return (u & 0x80000000u) ? ~u : (u | 0x80000000u);
}

__global__ __launch_bounds__(256, 4)
void k_topk_decode(float* __restrict__ lat,          // dense latents (in) -> sparse (out), in d_out
                   float* __restrict__ recon,
                   const float* __restrict__ WdT,    // [DS][DM]
                   const float* __restrict__ b_dec,
                   const int* __restrict__ kptr,
                   const float* __restrict__ x,      // fp64 refinement inputs
                   const float* __restrict__ W_enc,
                   const float* __restrict__ b_enc)
{
    __shared__ unsigned long long cand[512];   // packed (fkey<<32 | ~idx)
    __shared__ float  red[8];
    __shared__ float  sh_sig, sh_tau, sh_vk;
    __shared__ int    sh_cnt, sh_uc;
    __shared__ float  win_v[64];
    __shared__ int    win_i[64];
    __shared__ float  unc_v[64];
    __shared__ int    unc_i[64];
    __shared__ double unc_d[64];

    const int  t    = threadIdx.x;
    const int  lane = t & 63;
    const int  wave = t >> 6;
    const long row  = blockIdx.x;
    float* rowp = lat + row * (long)DS;
    int kk = *kptr; kk = min(max(kk, 1), 64);

    // stage the row in registers (nontemporal: don't evict WdT/W_enc from caches)
    f32x4 v[12];
#pragma unroll
    for (int j = 0; j < 12; ++j)
        v[j] = __builtin_nontemporal_load(((const f32x4*)rowp) + j * 256 + t);

    // ---- per-row mean/std (across-column latent distribution is Gaussian by CLT)
    float s1 = 0.f, s2 = 0.f;
#pragma unroll
    for (int j = 0; j < 12; ++j)
#pragma unroll
        for (int c = 0; c < 4; ++c) { float f = v[j][c]; s1 += f; s2 += f * f; }
#pragma unroll
    for (int off = 32; off; off >>= 1) { s1 += __shfl_down(s1, off); s2 += __shfl_down(s2, off); }
    if (lane == 0) { red[wave] = s1; red[4 + wave] = s2; }
    __syncthreads();
    if (t == 0) {
        float a = red[0] + red[1] + red[2] + red[3];
        float b = red[4] + red[5] + red[6] + red[7];
        float mu  = a / (float)DS;
        float var = b / (float)DS - mu * mu;
        float sig = sqrtf(fmaxf(var, 1e-12f));
        sh_sig = sig; sh_tau = mu + 2.2f * sig;   // E[#candidates] ~ 170
        sh_cnt = 0; sh_uc = 0;
    }
    __syncthreads();

    // ---- collect candidates > tau (retry loop for distribution-model safety)
    int C = 0;
    for (int it = 0; it < 8; ++it) {
        float tau = sh_tau;
#pragma unroll
        for (int j = 0; j < 12; ++j)
#pragma unroll
            for (int c = 0; c < 4; ++c) {
                float f = v[j][c];
                if (f > tau) {
                    int p = atomicAdd(&sh_cnt, 1);
                    if (p < 512) {
                        int idx = (j * 256 + t) * 4 + c;
                        cand[p] = ((unsigned long long)fkey(f) << 32)
                                | (unsigned long long)(0xFFFFFFFFu - (unsigned)idx);
                    }
                }
            }
        __syncthreads();
        C = sh_cnt;
        if (C >= kk && C <= 512) break;
        if (t == 0) {
            sh_cnt = 0;
            sh_tau = (C < kk) ? (tau - 0.7f * sh_sig - 1e-5f)
                              : (tau + 0.45f * sh_sig + 1e-5f);
        }
        __syncthreads();
    }
    if (C > 512) C = 512;

    // ---- wave-0 selection: kk rounds of 64-lane argmax over register-cached candidates
    if (t < 64) {
        unsigned long long e[8];
#pragma unroll
        for (int j = 0; j < 8; ++j) { int p = t + 64 * j; e[j] = (p < C) ? cand[p] : 0ULL; }
        for (int r = 0; r < kk; ++r) {
            unsigned long long m = e[0];
#pragma unroll
            for (int j = 1; j < 8; ++j) if (e[j] > m) m = e[j];
#pragma unroll
            for (int off = 32; off; off >>= 1) {
                unsigned long long o = __shfl_down(m, off);
                if (o > m) m = o;
            }
            m = __shfl(m, 0);
#pragma unroll
            for (int j = 0; j < 8; ++j) if (e[j] == m) e[j] = 0ULL;
            if (t == 0) {
                if (m) {
                    unsigned ku = (unsigned)(m >> 32);
                    win_v[r] = (ku & 0x80000000u) ? __uint_as_float(ku & 0x7FFFFFFFu)
                                                  : __uint_as_float(~ku);
                    win_i[r] = (int)(0xFFFFFFFFu - (unsigned)(m & 0xFFFFFFFFu));
                } else { win_v[r] = -3.0e38f; win_i[r] = r; }
            }
        }
        if (t == 0) sh_vk = win_v[kk - 1];
    }
    __syncthreads();

    // ---- fp64 refinement of near-boundary ties (EPS covers the dropped xl*w product error)
    const float vk  = sh_vk;
    const float EPS = 6e-3f;
#pragma unroll
    for (int j = 0; j < 12; ++j)
#pragma unroll
        for (int c = 0; c < 4; ++c) {
            float f = v[j][c];
            if (fabsf(f - vk) <= EPS) {
                int p = atomicAdd(&sh_uc, 1);
                if (p < 64) { unc_v[p] = f; unc_i[p] = (j * 256 + t) * 4 + c; }
            }
        }
    __syncthreads();
    const int un = min(sh_uc, 64);
    if (un > 1) {
        const float* xr = x + row * DM;
        for (int e = wave; e < un; e += 4) {
            const float* wr = W_enc + (long)unc_i[e] * DM;
            double s = 0.0;
            for (int d = lane; d < DM; d += 64) s += (double)xr[d] * (double)wr[d];
#pragma unroll
            for (int off = 32; off; off >>= 1) s += __shfl_down(s, off);
            if (lane == 0) unc_d[e] = s + (double)b_enc[unc_i[e]];
        }
        __syncthreads();
        if (t == 0) {
            int a = 0;
            for (int i = 0; i < kk; ++i)
                if (win_v[i] > vk + EPS) { win_v[a] = win_v[i]; win_i[a] = win_i[i]; ++a; }
            int need = kk - a;
            for (int s = 0; s < need; ++s) {
                int bj = -1, bi = 0x7fffffff; double bd = 0.0;
                for (int j = 0; j < un; ++j) {
                    if (unc_i[j] < 0) continue;
                    double dj = unc_d[j];
                    if (bj < 0 || dj > bd || (dj == bd && unc_i[j] < bi)) { bj = j; bd = dj; bi = unc_i[j]; }
                }
                win_v[a + s] = unc_v[bj]; win_i[a + s] = unc_i[bj];
                unc_i[bj] = -1;
            }
        }
        __syncthreads();
    }

    // ---- rewrite sparse row: zeros + scatter top-k (nontemporal)
    f32x4 z = {0.f, 0.f, 0.f, 0.f};
#pragma unroll
    for (int j = 0; j < 12; ++j)
        __builtin_nontemporal_store(z, ((f32x4*)rowp) + j * 256 + t);
    __syncthreads();
    if (t < kk) rowp[win_i[t]] = win_v[t];

    // ---- decode: recon[row][d] = b_dec[d] + sum_i v_i * WdT[s_i][d]
    float a0 = b_dec[t], a1 = b_dec[t + 256], a2 = b_dec[t + 512];
    for (int i = 0; i < kk; ++i) {
        float val = win_v[i];
        const float* w = WdT + (long)win_i[i] * DM;
        a0 += val * w[t];
        a1 += val * w[t + 256];
        a2 += val * w[t + 512];
    }
    float* rr = recon + row * DM;
    __builtin_nontemporal_store(a0, rr + t);
    __builtin_nontemporal_store(a1, rr + t + 256);
    __builtin_nontemporal_store(a2, rr + t + 512);
}

// ---------------------------------------------------------------- launch
extern "C" void kernel_launch(void* const* d_in, const int* in_sizes, int n_in,
                              void* d_out, int out_size, void* d_ws, size_t ws_size,
                              hipStream_t stream)
{
    const float* x     = (const float*)d_in[0];
    const float* W_enc = (const float*)d_in[1];
    const float* b_enc = (const float*)d_in[2];
    const float* W_dec = (const float*)d_in[3];
    const float* b_dec = (const float*)d_in[4];
    const int*   kptr  = (const int*)d_in[5];

    const int dmodel = in_sizes[4];               // 768
    const int dsae   = in_sizes[2];               // 12288
    const int M      = in_sizes[0] / dmodel;      // 8192

    float* recon  = (float*)d_out;                          // [M][DM]
    float* sparse = (float*)d_out + (size_t)M * dmodel;     // [M][DS] (also dense-latent scratch)

    char* ws = (char*)d_ws;
    _Float16* xh = (_Float16*)ws; ws += (size_t)M * dmodel * 2;
    _Float16* wh = (_Float16*)ws; ws += (size_t)dsae * dmodel * 2;
    _Float16* wl = (_Float16*)ws; ws += (size_t)dsae * dmodel * 2;
    float*   WdT = (float*)ws;    ws += (size_t)dsae * dmodel * 4;

    const int n4x = M * dmodel / 4;
    const int n4w = dsae * dmodel / 4;
    k_split1<<<(n4x + 255) / 256, 256, 0, stream>>>(x, xh, n4x, 16.0f);
    k_split<<<(n4w + 255) / 256, 256, 0, stream>>>(W_enc, wh, wl, n4w, 256.0f);
    k_transpose<<<dim3(dsae / 32, dmodel / 32), 256, 0, stream>>>(W_dec, WdT);
    k_encode<<<dim3(dsae / 128, M / 128), 256, 0, stream>>>(xh, wh, wl, b_enc, sparse);
    k_topk_decode<<<M, 256, 0, stream>>>(sparse, recon, WdT, b_dec, kptr, x, W_enc, b_enc);
}

// Round 4
// 1010.759 us; speedup vs baseline: 1.5270x; 1.1260x over previous
//
#include <hip/hip_runtime.h>
#include <hip/hip_fp16.h>

#define DM 768
#define DS 12288
#define CAP 384          // per-row candidate capacity
#define CTHR 2.25f       // tau = CTHR * sigma_row  -> E[count] ~ 150, SD ~ 12

typedef float    f32x4 __attribute__((ext_vector_type(4)));
typedef _Float16 f16x4 __attribute__((ext_vector_type(4)));
typedef _Float16 f16x8 __attribute__((ext_vector_type(8)));

typedef const __attribute__((address_space(1))) void* gas_t;
typedef __attribute__((address_space(3))) void* las_t;

__device__ __forceinline__ unsigned fkey(float f)
{
    unsigned u = __float_as_uint(f);
    return (u & 0x80000000u) ? ~u : (u | 0x80000000u);
}
__device__ __forceinline__ float ukey(unsigned k)
{
    return (k & 0x80000000u) ? __uint_as_float(k & 0x7FFFFFFFu) : __uint_as_float(~k);
}
__device__ __forceinline__ unsigned long long packci(float v, int col)
{
    return ((unsigned long long)fkey(v) << 32) | (unsigned long long)(0xFFFFFFFFu - (unsigned)col);
}

// ---------------------------------------------------------------- prep: x -> fp16 (x16), tau_row, zero cnt
__global__ __launch_bounds__(64)
void k_prep(const float* __restrict__ x, _Float16* __restrict__ xh,
            float* __restrict__ tau, unsigned* __restrict__ cnt)
{
    const int lane = threadIdx.x;
    const long row = blockIdx.x;
    const f32x4* xr = (const f32x4*)(x + row * DM);
    f32x4 v[3];
    float n2 = 0.f;
#pragma unroll
    for (int j = 0; j < 3; ++j) {
        v[j] = xr[lane + 64 * j];
#pragma unroll
        for (int c = 0; c < 4; ++c) n2 += v[j][c] * v[j][c];
    }
#pragma unroll
    for (int off = 32; off; off >>= 1) n2 += __shfl_down(n2, off);
    f16x4* xo = (f16x4*)(xh + row * DM);
#pragma unroll
    for (int j = 0; j < 3; ++j) {
        f16x4 h;
#pragma unroll
        for (int c = 0; c < 4; ++c) h[c] = (_Float16)(v[j][c] * 16.0f);
        xo[lane + 64 * j] = h;
    }
    if (lane == 0) {
        tau[row] = CTHR * sqrtf(n2 / 384.0f);   // sigma = ||x|| * sqrt(Var(U(+-sqrt(6/768)))) = ||x||/sqrt(384)
        cnt[row] = 0u;
    }
}

// ---------------------------------------------------------------- W_enc -> fp16 (x256)
__global__ void k_split1(const float* __restrict__ src, _Float16* __restrict__ hi,
                         int n4, float scale)
{
    int i = blockIdx.x * 256 + threadIdx.x;
    if (i >= n4) return;
    f32x4 v = ((const f32x4*)src)[i];
    f16x4 h;
#pragma unroll
    for (int j = 0; j < 4; ++j) h[j] = (_Float16)(v[j] * scale);
    ((f16x4*)hi)[i] = h;
}

// ---------------------------------------------------------------- transpose W_dec [DM][DS] -> [DS][DM]
__global__ void k_transpose(const float* __restrict__ W, float* __restrict__ WT)
{
    __shared__ float tile[32][33];
    int bx = blockIdx.x;            // DS/32
    int by = blockIdx.y;            // DM/32
    int tx = threadIdx.x & 31;
    int ty = threadIdx.x >> 5;      // 0..7
#pragma unroll
    for (int j = 0; j < 4; ++j) {
        int d = by * 32 + ty + j * 8;
        tile[ty + j * 8][tx] = W[(long)d * DS + bx * 32 + tx];
    }
    __syncthreads();
#pragma unroll
    for (int j = 0; j < 4; ++j) {
        int s = bx * 32 + ty + j * 8;
        WT[(long)s * DM + by * 32 + tx] = tile[tx][ty + j * 8];
    }
}

// ---------------------------------------------------------------- encode GEMM (1 MFMA product) + candidate compaction
__global__ __launch_bounds__(256, 4)
void k_encode(const _Float16* __restrict__ Ah, const _Float16* __restrict__ Bh,
              const float* __restrict__ b_enc, const float* __restrict__ tau,
              unsigned* __restrict__ cnt, unsigned long long* __restrict__ cand)
{
    __shared__ _Float16 sAh[128 * 64];
    __shared__ _Float16 sBh[128 * 64];
    __shared__ float    stau[128];

    const int t    = threadIdx.x;
    const int lane = t & 63;
    const int wave = t >> 6;
    const int bn   = blockIdx.x;        // DS/128
    const int bm   = blockIdx.y;        // M/128
    const int wm   = (wave & 1) * 64;
    const int wn   = (wave >> 1) * 64;
    const int lm   = lane & 15;
    const int quad = lane >> 4;

    f32x4 acc[4][4] = {};

    for (int kt = 0; kt < DM / 64; ++kt) {
        if (kt) __syncthreads();
        const int kbase = kt * 64;
#pragma unroll
        for (int i = 0; i < 4; ++i) {
            int L = i * 256 + t;
            int r = L >> 3;             // tile row 0..127
            int s = L & 7;              // lds slot
            int g = s ^ (r & 7);        // global slot fetched into lds slot s
            long aoff = (long)(bm * 128 + r) * DM + kbase + g * 8;
            long boff = (long)(bn * 128 + r) * DM + kbase + g * 8;
            __builtin_amdgcn_global_load_lds((gas_t)(Ah + aoff), (las_t)&sAh[L * 8], 16, 0, 0);
            __builtin_amdgcn_global_load_lds((gas_t)(Bh + boff), (las_t)&sBh[L * 8], 16, 0, 0);
        }
        __syncthreads();

#pragma unroll
        for (int kc = 0; kc < 2; ++kc) {
            f16x8 a_h[4], b_h[4];
#pragma unroll
            for (int mt = 0; mt < 4; ++mt) {
                int m = wm + mt * 16 + lm;
                int slot = (kc * 4 + quad) ^ (m & 7);
                a_h[mt] = *(const f16x8*)&sAh[m * 64 + slot * 8];
            }
#pragma unroll
            for (int nt = 0; nt < 4; ++nt) {
                int n = wn + nt * 16 + lm;
                int slot = (kc * 4 + quad) ^ (n & 7);
                b_h[nt] = *(const f16x8*)&sBh[n * 64 + slot * 8];
            }
#pragma unroll
            for (int mt = 0; mt < 4; ++mt)
#pragma unroll
                for (int nt = 0; nt < 4; ++nt)
                    acc[mt][nt] = __builtin_amdgcn_mfma_f32_16x16x32_f16(a_h[mt], b_h[nt], acc[mt][nt], 0, 0, 0);
        }
    }

    if (t < 128) stau[t] = tau[bm * 128 + t];
    __syncthreads();

    const float inv = 1.0f / 4096.0f;   // undo x*16, w*256 scaling
#pragma unroll
    for (int nt = 0; nt < 4; ++nt) {
        int col = bn * 128 + wn + nt * 16 + lm;
        float bias = b_enc[col];
#pragma unroll
        for (int mt = 0; mt < 4; ++mt) {
            int rbase = wm + mt * 16 + quad * 4;
#pragma unroll
            for (int r = 0; r < 4; ++r) {
                float val = acc[mt][nt][r] * inv + bias;
                if (val > stau[rbase + r]) {
                    int row = bm * 128 + rbase + r;
                    unsigned p = atomicAdd(&cnt[row], 1u);
                    if (p < CAP) cand[(long)row * CAP + p] = packci(val, col);
                }
            }
        }
    }
}

// ---------------------------------------------------------------- select + fp64 tie refine + scatter + decode
__global__ __launch_bounds__(256)
void k_select_decode(const unsigned long long* __restrict__ cand,
                     const unsigned* __restrict__ cnt,
                     const float* __restrict__ tau,
                     float* __restrict__ sparse, float* __restrict__ recon,
                     const float* __restrict__ WdT, const float* __restrict__ b_dec,
                     const int* __restrict__ kptr,
                     const float* __restrict__ x, const float* __restrict__ W_enc,
                     const float* __restrict__ b_enc)
{
    __shared__ unsigned long long sc[CAP];
    __shared__ float  win_v[64];
    __shared__ int    win_i[64];
    __shared__ float  unc_v[96];
    __shared__ int    unc_i[96];
    __shared__ double unc_d[96];
    __shared__ int    sh_cnt, sh_uc;
    __shared__ float  sh_vk;

    const int  t    = threadIdx.x;
    const int  lane = t & 63;
    const int  wave = t >> 6;
    const long row  = blockIdx.x;
    float* rowp = sparse + row * (long)DS;
    int kk = *kptr; kk = min(max(kk, 1), 64);
    int C = (int)cnt[row];
    if (t == 0) sh_uc = 0;

    if (C >= kk && C <= CAP) {
        for (int j = t; j < C; j += 256) sc[j] = cand[row * CAP + j];
        __syncthreads();
    } else {
        // ---- exact fallback (expected never): recompute the row, bit-search threshold
        const float* xr = x + row * DM;
        for (int c0 = t; c0 < DS; c0 += 256) {
            const float* wr = W_enc + (long)c0 * DM;
            float s = b_enc[c0];
            for (int d = 0; d < DM; ++d) s += xr[d] * wr[d];
            rowp[c0] = s;                       // rowp as scratch; zeroed later
        }
        __syncthreads();
        unsigned thr = 0;
        for (int b = 31; b >= 0; --b) {
            unsigned c2 = thr | (1u << b);
            if (t == 0) sh_cnt = 0;
            __syncthreads();
            for (int j = t; j < DS; j += 256)
                if (fkey(rowp[j]) >= c2) atomicAdd(&sh_cnt, 1);
            __syncthreads();
            if (sh_cnt >= kk) thr = c2;
            __syncthreads();
        }
        float tlo = ukey(thr) - 0.03f;
        if (t == 0) sh_cnt = 0;
        __syncthreads();
        for (int j = t; j < DS; j += 256) {
            float f = rowp[j];
            if (f >= tlo) {
                int p = atomicAdd(&sh_cnt, 1);
                if (p < CAP) sc[p] = packci(f, j);
            }
        }
        __syncthreads();
        C = min(sh_cnt, CAP);
    }

    // ---- wave-0 selection: kk rounds of 64-lane argmax over register-cached candidates
    if (t < 64) {
        unsigned long long e[CAP / 64];
#pragma unroll
        for (int j = 0; j < CAP / 64; ++j) { int p = t + 64 * j; e[j] = (p < C) ? sc[p] : 0ULL; }
        for (int r = 0; r < kk; ++r) {
            unsigned long long m = e[0];
#pragma unroll
            for (int j = 1; j < CAP / 64; ++j) if (e[j] > m) m = e[j];
#pragma unroll
            for (int off = 32; off; off >>= 1) {
                unsigned long long o = __shfl_down(m, off);
                if (o > m) m = o;
            }
            m = __shfl(m, 0);
#pragma unroll
            for (int j = 0; j < CAP / 64; ++j) if (e[j] == m) e[j] = 0ULL;
            if (t == 0) {
                if (m) {
                    win_v[r] = ukey((unsigned)(m >> 32));
                    win_i[r] = (int)(0xFFFFFFFFu - (unsigned)(m & 0xFFFFFFFFu));
                } else { win_v[r] = -3.0e38f; win_i[r] = r; }
            }
        }
        if (t == 0) sh_vk = win_v[kk - 1];
    }
    __syncthreads();

    // ---- fp64 refinement of near-boundary ties (EPS covers 1-product fp16 rounding error)
    const float vk  = sh_vk;
    const float EPS = 0.025f;
    for (int j = t; j < C; j += 256) {
        float f = ukey((unsigned)(sc[j] >> 32));
        if (fabsf(f - vk) <= EPS) {
            int p = atomicAdd(&sh_uc, 1);
            if (p < 96) { unc_v[p] = f; unc_i[p] = (int)(0xFFFFFFFFu - (unsigned)(sc[j] & 0xFFFFFFFFu)); }
        }
    }
    __syncthreads();
    const int un = min(sh_uc, 96);
    if (un > 1) {
        const float* xr = x + row * DM;
        for (int e = wave; e < un; e += 4) {
            const float* wr = W_enc + (long)unc_i[e] * DM;
            double s = 0.0;
            for (int d = lane; d < DM; d += 64) s += (double)xr[d] * (double)wr[d];
#pragma unroll
            for (int off = 32; off; off >>= 1) s += __shfl_down(s, off);
            if (lane == 0) unc_d[e] = s + (double)b_enc[unc_i[e]];
        }
        __syncthreads();
        if (t == 0) {
            int a = 0;
            for (int i = 0; i < kk; ++i)
                if (win_v[i] > vk + EPS) { win_v[a] = win_v[i]; win_i[a] = win_i[i]; ++a; }
            int need = kk - a;
            for (int s = 0; s < need; ++s) {
                int bj = -1, bi = 0x7fffffff; double bd = 0.0;
                for (int j = 0; j < un; ++j) {
                    if (unc_i[j] < 0) continue;
                    double dj = unc_d[j];
                    if (bj < 0 || dj > bd || (dj == bd && unc_i[j] < bi)) { bj = j; bd = dj; bi = unc_i[j]; }
                }
                win_v[a + s] = unc_v[bj]; win_i[a + s] = unc_i[bj];
                unc_i[bj] = -1;
            }
        }
        __syncthreads();
    }

    // ---- write sparse row: zeros + scatter top-k
    f32x4 z = {0.f, 0.f, 0.f, 0.f};
#pragma unroll
    for (int j = 0; j < 12; ++j)
        __builtin_nontemporal_store(z, ((f32x4*)rowp) + j * 256 + t);
    __syncthreads();
    if (t < kk) rowp[win_i[t]] = win_v[t];

    // ---- decode: recon[row][d] = b_dec[d] + sum_i v_i * WdT[s_i][d]
    float a0 = b_dec[t], a1 = b_dec[t + 256], a2 = b_dec[t + 512];
    for (int i = 0; i < kk; ++i) {
        float val = win_v[i];
        const float* w = WdT + (long)win_i[i] * DM;
        a0 += val * w[t];
        a1 += val * w[t + 256];
        a2 += val * w[t + 512];
    }
    float* rr = recon + row * DM;
    __builtin_nontemporal_store(a0, rr + t);
    __builtin_nontemporal_store(a1, rr + t + 256);
    __builtin_nontemporal_store(a2, rr + t + 512);
}

// ---------------------------------------------------------------- launch
extern "C" void kernel_launch(void* const* d_in, const int* in_sizes, int n_in,
                              void* d_out, int out_size, void* d_ws, size_t ws_size,
                              hipStream_t stream)
{
    const float* x     = (const float*)d_in[0];
    const float* W_enc = (const float*)d_in[1];
    const float* b_enc = (const float*)d_in[2];
    const float* W_dec = (const float*)d_in[3];
    const float* b_dec = (const float*)d_in[4];
    const int*   kptr  = (const int*)d_in[5];

    const int dmodel = in_sizes[4];               // 768
    const int dsae   = in_sizes[2];               // 12288
    const int M      = in_sizes[0] / dmodel;      // 8192

    float* recon  = (float*)d_out;                          // [M][DM]
    float* sparse = (float*)d_out + (size_t)M * dmodel;     // [M][DS]

    char* ws = (char*)d_ws;
    _Float16* xh  = (_Float16*)ws;          ws += (size_t)M * dmodel * 2;
    _Float16* wh  = (_Float16*)ws;          ws += (size_t)dsae * dmodel * 2;
    float*    WdT = (float*)ws;             ws += (size_t)dsae * dmodel * 4;
    unsigned long long* cand = (unsigned long long*)ws; ws += (size_t)M * CAP * 8;
    unsigned* cnt = (unsigned*)ws;          ws += (size_t)M * 4;
    float*    tau = (float*)ws;             ws += (size_t)M * 4;

    const int n4w = dsae * dmodel / 4;
    k_prep<<<M, 64, 0, stream>>>(x, xh, tau, cnt);
    k_split1<<<(n4w + 255) / 256, 256, 0, stream>>>(W_enc, wh, n4w, 256.0f);
    k_transpose<<<dim3(dsae / 32, dmodel / 32), 256, 0, stream>>>(W_dec, WdT);
    k_encode<<<dim3(dsae / 128, M / 128), 256, 0, stream>>>(xh, wh, b_enc, tau, cnt, cand);
    k_select_decode<<<M, 256, 0, stream>>>(cand, cnt, tau, sparse, recon, WdT, b_dec,
                                           kptr, x, W_enc, b_enc);
}

// Round 5
// 867.375 us; speedup vs baseline: 1.7794x; 1.1653x over previous
//
#include <hip/hip_runtime.h>
#include <hip/hip_fp16.h>

#define DM 768
#define DS 12288
#define CAP 384          // per-row candidate capacity
#define CTHR 2.25f       // tau = CTHR * sigma_row  -> E[count] ~ 150, SD ~ 12
#define SLOTS 6          // per-row LDS slots per 128-col block (overflow P ~ 9e-4 -> exact spill path)

typedef float    f32x4 __attribute__((ext_vector_type(4)));
typedef _Float16 f16x4 __attribute__((ext_vector_type(4)));
typedef _Float16 f16x8 __attribute__((ext_vector_type(8)));

typedef const __attribute__((address_space(1))) void* gas_t;
typedef __attribute__((address_space(3))) void* las_t;

__device__ __forceinline__ unsigned fkey(float f)
{
    unsigned u = __float_as_uint(f);
    return (u & 0x80000000u) ? ~u : (u | 0x80000000u);
}
__device__ __forceinline__ float ukey(unsigned k)
{
    return (k & 0x80000000u) ? __uint_as_float(k & 0x7FFFFFFFu) : __uint_as_float(~k);
}
__device__ __forceinline__ unsigned long long packci(float v, int col)
{
    return ((unsigned long long)fkey(v) << 32) | (unsigned long long)(0xFFFFFFFFu - (unsigned)col);
}

// ---------------------------------------------------------------- prep: x -> fp16 (x16), tau_row, zero cnt
__global__ __launch_bounds__(64)
void k_prep(const float* __restrict__ x, _Float16* __restrict__ xh,
            float* __restrict__ tau, unsigned* __restrict__ cnt)
{
    const int lane = threadIdx.x;
    const long row = blockIdx.x;
    const f32x4* xr = (const f32x4*)(x + row * DM);
    f32x4 v[3];
    float n2 = 0.f;
#pragma unroll
    for (int j = 0; j < 3; ++j) {
        v[j] = xr[lane + 64 * j];
#pragma unroll
        for (int c = 0; c < 4; ++c) n2 += v[j][c] * v[j][c];
    }
#pragma unroll
    for (int off = 32; off; off >>= 1) n2 += __shfl_down(n2, off);
    f16x4* xo = (f16x4*)(xh + row * DM);
#pragma unroll
    for (int j = 0; j < 3; ++j) {
        f16x4 h;
#pragma unroll
        for (int c = 0; c < 4; ++c) h[c] = (_Float16)(v[j][c] * 16.0f);
        xo[lane + 64 * j] = h;
    }
    if (lane == 0) {
        tau[row] = CTHR * sqrtf(n2 / 384.0f);   // sigma = ||x||/sqrt(384) for U(+-sqrt(6/768)) weights
        cnt[row] = 0u;
    }
}

// ---------------------------------------------------------------- W_enc -> fp16 (x256)
__global__ void k_split1(const float* __restrict__ src, _Float16* __restrict__ hi,
                         int n4, float scale)
{
    int i = blockIdx.x * 256 + threadIdx.x;
    if (i >= n4) return;
    f32x4 v = ((const f32x4*)src)[i];
    f16x4 h;
#pragma unroll
    for (int j = 0; j < 4; ++j) h[j] = (_Float16)(v[j] * scale);
    ((f16x4*)hi)[i] = h;
}

// ---------------------------------------------------------------- transpose W_dec [DM][DS] -> [DS][DM]
__global__ void k_transpose(const float* __restrict__ W, float* __restrict__ WT)
{
    __shared__ float tile[32][33];
    int bx = blockIdx.x;            // DS/32
    int by = blockIdx.y;            // DM/32
    int tx = threadIdx.x & 31;
    int ty = threadIdx.x >> 5;      // 0..7
#pragma unroll
    for (int j = 0; j < 4; ++j) {
        int d = by * 32 + ty + j * 8;
        tile[ty + j * 8][tx] = W[(long)d * DS + bx * 32 + tx];
    }
    __syncthreads();
#pragma unroll
    for (int j = 0; j < 4; ++j) {
        int s = bx * 32 + ty + j * 8;
        WT[(long)s * DM + by * 32 + tx] = tile[tx][ty + j * 8];
    }
}

// ---------------------------------------------------------------- encode GEMM + LDS-compacted candidate emit
__global__ __launch_bounds__(256, 4)
void k_encode(const _Float16* __restrict__ Ah, const _Float16* __restrict__ Bh,
              const float* __restrict__ b_enc, const float* __restrict__ tau,
              unsigned* __restrict__ cnt, unsigned long long* __restrict__ cand)
{
    __shared__ _Float16 sAh[128 * 64];
    __shared__ _Float16 sBh[128 * 64];
    __shared__ float    stau[128];
    __shared__ unsigned srcnt[128];
    __shared__ unsigned long long slist[128 * SLOTS];

    const int t    = threadIdx.x;
    const int lane = t & 63;
    const int wave = t >> 6;
    const int bn   = blockIdx.x;        // DS/128
    const int bm   = blockIdx.y;        // M/128
    const int wm   = (wave & 1) * 64;
    const int wn   = (wave >> 1) * 64;
    const int lm   = lane & 15;
    const int quad = lane >> 4;

    if (t < 128) { stau[t] = tau[bm * 128 + t]; srcnt[t] = 0u; }

    f32x4 acc[4][4] = {};

    for (int kt = 0; kt < DM / 64; ++kt) {
        if (kt) __syncthreads();
        const int kbase = kt * 64;
#pragma unroll
        for (int i = 0; i < 4; ++i) {
            int L = i * 256 + t;
            int r = L >> 3;             // tile row 0..127
            int s = L & 7;              // lds slot
            int g = s ^ (r & 7);        // global slot fetched into lds slot s
            long aoff = (long)(bm * 128 + r) * DM + kbase + g * 8;
            long boff = (long)(bn * 128 + r) * DM + kbase + g * 8;
            __builtin_amdgcn_global_load_lds((gas_t)(Ah + aoff), (las_t)&sAh[L * 8], 16, 0, 0);
            __builtin_amdgcn_global_load_lds((gas_t)(Bh + boff), (las_t)&sBh[L * 8], 16, 0, 0);
        }
        __syncthreads();

#pragma unroll
        for (int kc = 0; kc < 2; ++kc) {
            f16x8 a_h[4], b_h[4];
#pragma unroll
            for (int mt = 0; mt < 4; ++mt) {
                int m = wm + mt * 16 + lm;
                int slot = (kc * 4 + quad) ^ (m & 7);
                a_h[mt] = *(const f16x8*)&sAh[m * 64 + slot * 8];
            }
#pragma unroll
            for (int nt = 0; nt < 4; ++nt) {
                int n = wn + nt * 16 + lm;
                int slot = (kc * 4 + quad) ^ (n & 7);
                b_h[nt] = *(const f16x8*)&sBh[n * 64 + slot * 8];
            }
#pragma unroll
            for (int mt = 0; mt < 4; ++mt)
#pragma unroll
                for (int nt = 0; nt < 4; ++nt)
                    acc[mt][nt] = __builtin_amdgcn_mfma_f32_16x16x32_f16(a_h[mt], b_h[nt], acc[mt][nt], 0, 0, 0);
        }
    }

    // ---- candidate push into per-row LDS lists (no dependent global-atomic chains)
    const float inv = 1.0f / 4096.0f;   // undo x*16, w*256 scaling
#pragma unroll
    for (int nt = 0; nt < 4; ++nt) {
        int col = bn * 128 + wn + nt * 16 + lm;
        float bias = b_enc[col];
#pragma unroll
        for (int mt = 0; mt < 4; ++mt) {
            int rbase = wm + mt * 16 + quad * 4;
#pragma unroll
            for (int r = 0; r < 4; ++r) {
                float val = acc[mt][nt][r] * inv + bias;
                if (val > stau[rbase + r]) {
                    int rl = rbase + r;
                    unsigned s = atomicAdd(&srcnt[rl], 1u);
                    if (s < SLOTS) slist[rl * SLOTS + s] = packci(val, col);
                    else {          // rare overflow: exact global path
                        int row = bm * 128 + rl;
                        unsigned p = atomicAdd(&cnt[row], 1u);
                        if (p < CAP) cand[(long)row * CAP + p] = packci(val, col);
                    }
                }
            }
        }
    }
    __syncthreads();

    // ---- one parallel reservation round per block: lane t<128 owns row t
    if (t < 128) {
        unsigned n = srcnt[t]; n = n < SLOTS ? n : SLOTS;
        if (n) {
            int row = bm * 128 + t;
            unsigned base = atomicAdd(&cnt[row], n);
            for (unsigned j = 0; j < n; ++j)
                if (base + j < CAP)
                    cand[(long)row * CAP + base + j] = slist[t * SLOTS + j];
        }
    }
}

// ---------------------------------------------------------------- select + fp64 tie refine + scatter + decode
__global__ __launch_bounds__(256)
void k_select_decode(const unsigned long long* __restrict__ cand,
                     const unsigned* __restrict__ cnt,
                     const float* __restrict__ tau,
                     float* __restrict__ sparse, float* __restrict__ recon,
                     const float* __restrict__ WdT, const float* __restrict__ b_dec,
                     const int* __restrict__ kptr,
                     const float* __restrict__ x, const float* __restrict__ W_enc,
                     const float* __restrict__ b_enc)
{
    __shared__ unsigned long long sc[CAP];
    __shared__ unsigned bmap[DS / 32];      // winner bitmap (384 words)
    __shared__ float  win_v[64];
    __shared__ int    win_i[64];
    __shared__ float  unc_v[96];
    __shared__ int    unc_i[96];
    __shared__ double unc_d[96];
    __shared__ int    sh_cnt, sh_uc;
    __shared__ float  sh_vk;

    const int  t    = threadIdx.x;
    const int  lane = t & 63;
    const int  wave = t >> 6;
    const long row  = blockIdx.x;
    float* rowp = sparse + row * (long)DS;
    int kk = *kptr; kk = min(max(kk, 1), 64);
    int C = (int)cnt[row];
    if (t == 0) sh_uc = 0;
    for (int j = t; j < DS / 32; j += 256) bmap[j] = 0u;

    if (C >= kk && C <= CAP) {
        for (int j = t; j < C; j += 256) sc[j] = cand[row * CAP + j];
        __syncthreads();
    } else {
        // ---- exact fallback (expected never): recompute the row, bit-search threshold
        const float* xr = x + row * DM;
        for (int c0 = t; c0 < DS; c0 += 256) {
            const float* wr = W_enc + (long)c0 * DM;
            float s = b_enc[c0];
            for (int d = 0; d < DM; ++d) s += xr[d] * wr[d];
            rowp[c0] = s;                       // rowp as scratch; overwritten by bitmap store pass
        }
        __syncthreads();
        unsigned thr = 0;
        for (int b = 31; b >= 0; --b) {
            unsigned c2 = thr | (1u << b);
            if (t == 0) sh_cnt = 0;
            __syncthreads();
            for (int j = t; j < DS; j += 256)
                if (fkey(rowp[j]) >= c2) atomicAdd(&sh_cnt, 1);
            __syncthreads();
            if (sh_cnt >= kk) thr = c2;
            __syncthreads();
        }
        float tlo = ukey(thr) - 0.03f;
        if (t == 0) sh_cnt = 0;
        __syncthreads();
        for (int j = t; j < DS; j += 256) {
            float f = rowp[j];
            if (f >= tlo) {
                int p = atomicAdd(&sh_cnt, 1);
                if (p < CAP) sc[p] = packci(f, j);
            }
        }
        __syncthreads();
        C = min(sh_cnt, CAP);
    }

    // ---- wave-0 selection: kk rounds of 64-lane argmax over register-cached candidates
    if (t < 64) {
        unsigned long long e[CAP / 64];
#pragma unroll
        for (int j = 0; j < CAP / 64; ++j) { int p = t + 64 * j; e[j] = (p < C) ? sc[p] : 0ULL; }
        for (int r = 0; r < kk; ++r) {
            unsigned long long m = e[0];
#pragma unroll
            for (int j = 1; j < CAP / 64; ++j) if (e[j] > m) m = e[j];
#pragma unroll
            for (int off = 32; off; off >>= 1) {
                unsigned long long o = __shfl_down(m, off);
                if (o > m) m = o;
            }
            m = __shfl(m, 0);
#pragma unroll
            for (int j = 0; j < CAP / 64; ++j) if (e[j] == m) e[j] = 0ULL;
            if (t == 0) {
                if (m) {
                    win_v[r] = ukey((unsigned)(m >> 32));
                    win_i[r] = (int)(0xFFFFFFFFu - (unsigned)(m & 0xFFFFFFFFu));
                } else { win_v[r] = -3.0e38f; win_i[r] = r; }
            }
        }
        if (t == 0) sh_vk = win_v[kk - 1];
    }
    __syncthreads();

    // ---- fp64 refinement of near-boundary ties (EPS covers 1-product fp16 rounding error)
    const float vk  = sh_vk;
    const float EPS = 0.025f;
    for (int j = t; j < C; j += 256) {
        float f = ukey((unsigned)(sc[j] >> 32));
        if (fabsf(f - vk) <= EPS) {
            int p = atomicAdd(&sh_uc, 1);
            if (p < 96) { unc_v[p] = f; unc_i[p] = (int)(0xFFFFFFFFu - (unsigned)(sc[j] & 0xFFFFFFFFu)); }
        }
    }
    __syncthreads();
    const int un = min(sh_uc, 96);
    if (un > 1) {
        const float* xr = x + row * DM;
        for (int e = wave; e < un; e += 4) {
            const float* wr = W_enc + (long)unc_i[e] * DM;
            double s = 0.0;
            for (int d = lane; d < DM; d += 64) s += (double)xr[d] * (double)wr[d];
#pragma unroll
            for (int off = 32; off; off >>= 1) s += __shfl_down(s, off);
            if (lane == 0) unc_d[e] = s + (double)b_enc[unc_i[e]];
        }
        __syncthreads();
        if (t == 0) {
            int a = 0;
            for (int i = 0; i < kk; ++i)
                if (win_v[i] > vk + EPS) { win_v[a] = win_v[i]; win_i[a] = win_i[i]; ++a; }
            int need = kk - a;
            for (int s = 0; s < need; ++s) {
                int bj = -1, bi = 0x7fffffff; double bd = 0.0;
                for (int j = 0; j < un; ++j) {
                    if (unc_i[j] < 0) continue;
                    double dj = unc_d[j];
                    if (bj < 0 || dj > bd || (dj == bd && unc_i[j] < bi)) { bj = j; bd = dj; bi = unc_i[j]; }
                }
                win_v[a + s] = unc_v[bj]; win_i[a + s] = unc_i[bj];
                unc_i[bj] = -1;
            }
        }
        __syncthreads();
    }

    // ---- write sparse row in ONE pass: zeros merged with winners via bitmap
    if (t < kk) atomicOr(&bmap[win_i[t] >> 5], 1u << (win_i[t] & 31));
    __syncthreads();
#pragma unroll
    for (int j = 0; j < 12; ++j) {
        int c4 = j * 256 + t;                   // f32x4 chunk index
        unsigned bits = (bmap[c4 >> 3] >> ((c4 & 7) * 4)) & 0xFu;
        f32x4 o = {0.f, 0.f, 0.f, 0.f};
        if (bits) {
#pragma unroll
            for (int b = 0; b < 4; ++b)
                if (bits & (1u << b)) {
                    int col = c4 * 4 + b;
                    for (int i = 0; i < kk; ++i)
                        if (win_i[i] == col) { o[b] = win_v[i]; break; }
                }
        }
        __builtin_nontemporal_store(o, ((f32x4*)rowp) + c4);
    }

    // ---- decode: recon[row][d] = b_dec[d] + sum_i v_i * WdT[s_i][d]
    float a0 = b_dec[t], a1 = b_dec[t + 256], a2 = b_dec[t + 512];
    for (int i = 0; i < kk; ++i) {
        float val = win_v[i];
        const float* w = WdT + (long)win_i[i] * DM;
        a0 += val * w[t];
        a1 += val * w[t + 256];
        a2 += val * w[t + 512];
    }
    float* rr = recon + row * DM;
    __builtin_nontemporal_store(a0, rr + t);
    __builtin_nontemporal_store(a1, rr + t + 256);
    __builtin_nontemporal_store(a2, rr + t + 512);
}

// ---------------------------------------------------------------- launch
extern "C" void kernel_launch(void* const* d_in, const int* in_sizes, int n_in,
                              void* d_out, int out_size, void* d_ws, size_t ws_size,
                              hipStream_t stream)
{
    const float* x     = (const float*)d_in[0];
    const float* W_enc = (const float*)d_in[1];
    const float* b_enc = (const float*)d_in[2];
    const float* W_dec = (const float*)d_in[3];
    const float* b_dec = (const float*)d_in[4];
    const int*   kptr  = (const int*)d_in[5];

    const int dmodel = in_sizes[4];               // 768
    const int dsae   = in_sizes[2];               // 12288
    const int M      = in_sizes[0] / dmodel;      // 8192

    float* recon  = (float*)d_out;                          // [M][DM]
    float* sparse = (float*)d_out + (size_t)M * dmodel;     // [M][DS]

    char* ws = (char*)d_ws;
    _Float16* xh  = (_Float16*)ws;          ws += (size_t)M * dmodel * 2;
    _Float16* wh  = (_Float16*)ws;          ws += (size_t)dsae * dmodel * 2;
    float*    WdT = (float*)ws;             ws += (size_t)dsae * dmodel * 4;
    unsigned long long* cand = (unsigned long long*)ws; ws += (size_t)M * CAP * 8;
    unsigned* cnt = (unsigned*)ws;          ws += (size_t)M * 4;
    float*    tau = (float*)ws;             ws += (size_t)M * 4;

    const int n4w = dsae * dmodel / 4;
    k_prep<<<M, 64, 0, stream>>>(x, xh, tau, cnt);
    k_split1<<<(n4w + 255) / 256, 256, 0, stream>>>(W_enc, wh, n4w, 256.0f);
    k_transpose<<<dim3(dsae / 32, dmodel / 32), 256, 0, stream>>>(W_dec, WdT);
    k_encode<<<dim3(dsae / 128, M / 128), 256, 0, stream>>>(xh, wh, b_enc, tau, cnt, cand);
    k_select_decode<<<M, 256, 0, stream>>>(cand, cnt, tau, sparse, recon, WdT, b_dec,
                                           kptr, x, W_enc, b_enc);
}

// Round 6
// 835.393 us; speedup vs baseline: 1.8475x; 1.0383x over previous
//
#include <hip/hip_runtime.h>
#include <hip/hip_fp16.h>

#define DM 768
#define DS 12288
#define CAP 384          // per-row candidate capacity
#define CTHR 2.25f       // tau = CTHR * sigma_row  -> E[count] ~ 150, SD ~ 12
#define SLOTS 6          // per-row LDS slots per 128-col block (overflow P ~ 9e-4 -> exact spill path)
#define GRPM 16          // bm-supertile for XCD/L2 locality

typedef float    f32x4 __attribute__((ext_vector_type(4)));
typedef _Float16 f16x4 __attribute__((ext_vector_type(4)));
typedef _Float16 f16x8 __attribute__((ext_vector_type(8)));

typedef const __attribute__((address_space(1))) void* gas_t;
typedef __attribute__((address_space(3))) void* las_t;

__device__ __forceinline__ unsigned fkey(float f)
{
    unsigned u = __float_as_uint(f);
    return (u & 0x80000000u) ? ~u : (u | 0x80000000u);
}
__device__ __forceinline__ float ukey(unsigned k)
{
    return (k & 0x80000000u) ? __uint_as_float(k & 0x7FFFFFFFu) : __uint_as_float(~k);
}
__device__ __forceinline__ unsigned long long packci(float v, int col)
{
    return ((unsigned long long)fkey(v) << 32) | (unsigned long long)(0xFFFFFFFFu - (unsigned)col);
}

// ---------------------------------------------------------------- prep: x -> fp16 (x16), tau_row, zero cnt
__global__ __launch_bounds__(64)
void k_prep(const float* __restrict__ x, _Float16* __restrict__ xh,
            float* __restrict__ tau, unsigned* __restrict__ cnt)
{
    const int lane = threadIdx.x;
    const long row = blockIdx.x;
    const f32x4* xr = (const f32x4*)(x + row * DM);
    f32x4 v[3];
    float n2 = 0.f;
#pragma unroll
    for (int j = 0; j < 3; ++j) {
        v[j] = xr[lane + 64 * j];
#pragma unroll
        for (int c = 0; c < 4; ++c) n2 += v[j][c] * v[j][c];
    }
#pragma unroll
    for (int off = 32; off; off >>= 1) n2 += __shfl_down(n2, off);
    f16x4* xo = (f16x4*)(xh + row * DM);
#pragma unroll
    for (int j = 0; j < 3; ++j) {
        f16x4 h;
#pragma unroll
        for (int c = 0; c < 4; ++c) h[c] = (_Float16)(v[j][c] * 16.0f);
        xo[lane + 64 * j] = h;
    }
    if (lane == 0) {
        tau[row] = CTHR * sqrtf(n2 / 384.0f);   // sigma = ||x||/sqrt(384) for U(+-sqrt(6/768)) weights
        cnt[row] = 0u;
    }
}

// ---------------------------------------------------------------- W_enc -> fp16 (x256)
__global__ void k_split1(const float* __restrict__ src, _Float16* __restrict__ hi,
                         int n4, float scale)
{
    int i = blockIdx.x * 256 + threadIdx.x;
    if (i >= n4) return;
    f32x4 v = ((const f32x4*)src)[i];
    f16x4 h;
#pragma unroll
    for (int j = 0; j < 4; ++j) h[j] = (_Float16)(v[j] * scale);
    ((f16x4*)hi)[i] = h;
}

// ---------------------------------------------------------------- transpose W_dec [DM][DS] -> [DS][DM]
__global__ void k_transpose(const float* __restrict__ W, float* __restrict__ WT)
{
    __shared__ float tile[32][33];
    int bx = blockIdx.x;            // DS/32
    int by = blockIdx.y;            // DM/32
    int tx = threadIdx.x & 31;
    int ty = threadIdx.x >> 5;      // 0..7
#pragma unroll
    for (int j = 0; j < 4; ++j) {
        int d = by * 32 + ty + j * 8;
        tile[ty + j * 8][tx] = W[(long)d * DS + bx * 32 + tx];
    }
    __syncthreads();
#pragma unroll
    for (int j = 0; j < 4; ++j) {
        int s = bx * 32 + ty + j * 8;
        WT[(long)s * DM + by * 32 + tx] = tile[tx][ty + j * 8];
    }
}

// ---------------------------------------------------------------- encode GEMM + LDS-compacted candidate emit
// 1D grid with bm-supertile swizzle: consecutive blocks sweep 16 bm values, so each
// XCD (round-robin over dispatch index) keeps 2 A-panels L2-resident and B-panel
// L3 traffic drops ~2x vs bn-fastest order.
__global__ __launch_bounds__(256, 4)
void k_encode(const _Float16* __restrict__ Ah, const _Float16* __restrict__ Bh,
              const float* __restrict__ b_enc, const float* __restrict__ tau,
              unsigned* __restrict__ cnt, unsigned long long* __restrict__ cand)
{
    __shared__ _Float16 sAh[128 * 64];
    __shared__ _Float16 sBh[128 * 64];
    __shared__ float    stau[128];
    __shared__ unsigned srcnt[128];
    __shared__ unsigned long long slist[128 * SLOTS];

    const int t    = threadIdx.x;
    const int lane = t & 63;
    const int wave = t >> 6;
    const int id   = blockIdx.x;
    const int per  = GRPM * (DS / 128);          // blocks per supertile
    const int sid  = id / per;
    const int rem  = id % per;
    const int bm   = sid * GRPM + (rem & (GRPM - 1));
    const int bn   = rem / GRPM;
    const int wm   = (wave & 1) * 64;
    const int wn   = (wave >> 1) * 64;
    const int lm   = lane & 15;
    const int quad = lane >> 4;

    if (t < 128) { stau[t] = tau[bm * 128 + t]; srcnt[t] = 0u; }

    f32x4 acc[4][4] = {};

    for (int kt = 0; kt < DM / 64; ++kt) {
        if (kt) __syncthreads();
        const int kbase = kt * 64;
#pragma unroll
        for (int i = 0; i < 4; ++i) {
            int L = i * 256 + t;
            int r = L >> 3;             // tile row 0..127
            int s = L & 7;              // lds slot
            int g = s ^ (r & 7);        // global slot fetched into lds slot s
            long aoff = (long)(bm * 128 + r) * DM + kbase + g * 8;
            long boff = (long)(bn * 128 + r) * DM + kbase + g * 8;
            __builtin_amdgcn_global_load_lds((gas_t)(Ah + aoff), (las_t)&sAh[L * 8], 16, 0, 0);
            __builtin_amdgcn_global_load_lds((gas_t)(Bh + boff), (las_t)&sBh[L * 8], 16, 0, 0);
        }
        __syncthreads();

#pragma unroll
        for (int kc = 0; kc < 2; ++kc) {
            f16x8 a_h[4], b_h[4];
#pragma unroll
            for (int mt = 0; mt < 4; ++mt) {
                int m = wm + mt * 16 + lm;
                int slot = (kc * 4 + quad) ^ (m & 7);
                a_h[mt] = *(const f16x8*)&sAh[m * 64 + slot * 8];
            }
#pragma unroll
            for (int nt = 0; nt < 4; ++nt) {
                int n = wn + nt * 16 + lm;
                int slot = (kc * 4 + quad) ^ (n & 7);
                b_h[nt] = *(const f16x8*)&sBh[n * 64 + slot * 8];
            }
#pragma unroll
            for (int mt = 0; mt < 4; ++mt)
#pragma unroll
                for (int nt = 0; nt < 4; ++nt)
                    acc[mt][nt] = __builtin_amdgcn_mfma_f32_16x16x32_f16(a_h[mt], b_h[nt], acc[mt][nt], 0, 0, 0);
        }
    }

    // ---- candidate push into per-row LDS lists (no dependent global-atomic chains)
    const float inv = 1.0f / 4096.0f;   // undo x*16, w*256 scaling
#pragma unroll
    for (int nt = 0; nt < 4; ++nt) {
        int col = bn * 128 + wn + nt * 16 + lm;
        float bias = b_enc[col];
#pragma unroll
        for (int mt = 0; mt < 4; ++mt) {
            int rbase = wm + mt * 16 + quad * 4;
#pragma unroll
            for (int r = 0; r < 4; ++r) {
                float val = acc[mt][nt][r] * inv + bias;
                if (val > stau[rbase + r]) {
                    int rl = rbase + r;
                    unsigned s = atomicAdd(&srcnt[rl], 1u);
                    if (s < SLOTS) slist[rl * SLOTS + s] = packci(val, col);
                    else {          // rare overflow: exact global path
                        int row = bm * 128 + rl;
                        unsigned p = atomicAdd(&cnt[row], 1u);
                        if (p < CAP) cand[(long)row * CAP + p] = packci(val, col);
                    }
                }
            }
        }
    }
    __syncthreads();

    // ---- one parallel reservation round per block: lane t<128 owns row t
    if (t < 128) {
        unsigned n = srcnt[t]; n = n < SLOTS ? n : SLOTS;
        if (n) {
            int row = bm * 128 + t;
            unsigned base = atomicAdd(&cnt[row], n);
            for (unsigned j = 0; j < n; ++j)
                if (base + j < CAP)
                    cand[(long)row * CAP + base + j] = slist[t * SLOTS + j];
        }
    }
}

// ---------------------------------------------------------------- select + fp64 tie refine + scatter + decode
__global__ __launch_bounds__(256)
void k_select_decode(const unsigned long long* __restrict__ cand,
                     const unsigned* __restrict__ cnt,
                     const float* __restrict__ tau,
                     float* __restrict__ sparse, float* __restrict__ recon,
                     const float* __restrict__ WdT, const float* __restrict__ b_dec,
                     const int* __restrict__ kptr,
                     const float* __restrict__ x, const float* __restrict__ W_enc,
                     const float* __restrict__ b_enc)
{
    __shared__ unsigned long long sc[CAP];
    __shared__ unsigned bmap[DS / 32];      // winner bitmap (384 words)
    __shared__ float  win_v[64];
    __shared__ int    win_i[64];
    __shared__ float  unc_v[96];
    __shared__ int    unc_i[96];
    __shared__ double unc_d[96];
    __shared__ int    sh_cnt, sh_uc;
    __shared__ float  sh_vk;

    const int  t    = threadIdx.x;
    const int  lane = t & 63;
    const int  wave = t >> 6;
    const long row  = blockIdx.x;
    float* rowp = sparse + row * (long)DS;
    int kk = *kptr; kk = min(max(kk, 1), 64);
    int C = (int)cnt[row];
    if (t == 0) sh_uc = 0;
    for (int j = t; j < DS / 32; j += 256) bmap[j] = 0u;

    if (C >= kk && C <= CAP) {
        for (int j = t; j < C; j += 256) sc[j] = cand[row * CAP + j];
        __syncthreads();
    } else {
        // ---- exact fallback (expected never): recompute the row, bit-search threshold
        const float* xr = x + row * DM;
        for (int c0 = t; c0 < DS; c0 += 256) {
            const float* wr = W_enc + (long)c0 * DM;
            float s = b_enc[c0];
            for (int d = 0; d < DM; ++d) s += xr[d] * wr[d];
            rowp[c0] = s;                       // rowp as scratch; overwritten by bitmap store pass
        }
        __syncthreads();
        unsigned thr = 0;
        for (int b = 31; b >= 0; --b) {
            unsigned c2 = thr | (1u << b);
            if (t == 0) sh_cnt = 0;
            __syncthreads();
            for (int j = t; j < DS; j += 256)
                if (fkey(rowp[j]) >= c2) atomicAdd(&sh_cnt, 1);
            __syncthreads();
            if (sh_cnt >= kk) thr = c2;
            __syncthreads();
        }
        float tlo = ukey(thr) - 0.03f;
        if (t == 0) sh_cnt = 0;
        __syncthreads();
        for (int j = t; j < DS; j += 256) {
            float f = rowp[j];
            if (f >= tlo) {
                int p = atomicAdd(&sh_cnt, 1);
                if (p < CAP) sc[p] = packci(f, j);
            }
        }
        __syncthreads();
        C = min(sh_cnt, CAP);
    }

    // ---- wave-0 selection: kk rounds of 64-lane argmax over register-cached candidates
    if (t < 64) {
        unsigned long long e[CAP / 64];
#pragma unroll
        for (int j = 0; j < CAP / 64; ++j) { int p = t + 64 * j; e[j] = (p < C) ? sc[p] : 0ULL; }
        for (int r = 0; r < kk; ++r) {
            unsigned long long m = e[0];
#pragma unroll
            for (int j = 1; j < CAP / 64; ++j) if (e[j] > m) m = e[j];
#pragma unroll
            for (int off = 32; off; off >>= 1) {
                unsigned long long o = __shfl_down(m, off);
                if (o > m) m = o;
            }
            m = __shfl(m, 0);
#pragma unroll
            for (int j = 0; j < CAP / 64; ++j) if (e[j] == m) e[j] = 0ULL;
            if (t == 0) {
                if (m) {
                    win_v[r] = ukey((unsigned)(m >> 32));
                    win_i[r] = (int)(0xFFFFFFFFu - (unsigned)(m & 0xFFFFFFFFu));
                } else { win_v[r] = -3.0e38f; win_i[r] = r; }
            }
        }
        if (t == 0) sh_vk = win_v[kk - 1];
    }
    __syncthreads();

    // ---- fp64 refinement of near-boundary ties.
    // 1-product fp16 latent error: rms ~6e-4, <=~5e-3 at 8 sigma; EPS=0.012 covers all
    // possible boundary-crossers with 2.4x margin (was 0.025 -> halves refine traffic).
    const float vk  = sh_vk;
    const float EPS = 0.012f;
    for (int j = t; j < C; j += 256) {
        float f = ukey((unsigned)(sc[j] >> 32));
        if (fabsf(f - vk) <= EPS) {
            int p = atomicAdd(&sh_uc, 1);
            if (p < 96) { unc_v[p] = f; unc_i[p] = (int)(0xFFFFFFFFu - (unsigned)(sc[j] & 0xFFFFFFFFu)); }
        }
    }
    __syncthreads();
    const int un = min(sh_uc, 96);
    if (un > 1) {
        const float* xr = x + row * DM;
        for (int e = wave; e < un; e += 4) {
            const float* wr = W_enc + (long)unc_i[e] * DM;
            double s = 0.0;
            for (int d = lane; d < DM; d += 64) s += (double)xr[d] * (double)wr[d];
#pragma unroll
            for (int off = 32; off; off >>= 1) s += __shfl_down(s, off);
            if (lane == 0) unc_d[e] = s + (double)b_enc[unc_i[e]];
        }
        __syncthreads();
        if (t == 0) {
            int a = 0;
            for (int i = 0; i < kk; ++i)
                if (win_v[i] > vk + EPS) { win_v[a] = win_v[i]; win_i[a] = win_i[i]; ++a; }
            int need = kk - a;
            for (int s = 0; s < need; ++s) {
                int bj = -1, bi = 0x7fffffff; double bd = 0.0;
                for (int j = 0; j < un; ++j) {
                    if (unc_i[j] < 0) continue;
                    double dj = unc_d[j];
                    if (bj < 0 || dj > bd || (dj == bd && unc_i[j] < bi)) { bj = j; bd = dj; bi = unc_i[j]; }
                }
                win_v[a + s] = unc_v[bj]; win_i[a + s] = unc_i[bj];
                unc_i[bj] = -1;
            }
        }
        __syncthreads();
    }

    // ---- write sparse row in ONE pass: zeros merged with winners via bitmap
    if (t < kk) atomicOr(&bmap[win_i[t] >> 5], 1u << (win_i[t] & 31));
    __syncthreads();
#pragma unroll
    for (int j = 0; j < 12; ++j) {
        int c4 = j * 256 + t;                   // f32x4 chunk index
        unsigned bits = (bmap[c4 >> 3] >> ((c4 & 7) * 4)) & 0xFu;
        f32x4 o = {0.f, 0.f, 0.f, 0.f};
        if (bits) {
#pragma unroll
            for (int b = 0; b < 4; ++b)
                if (bits & (1u << b)) {
                    int col = c4 * 4 + b;
                    for (int i = 0; i < kk; ++i)
                        if (win_i[i] == col) { o[b] = win_v[i]; break; }
                }
        }
        __builtin_nontemporal_store(o, ((f32x4*)rowp) + c4);
    }

    // ---- decode: recon[row][d] = b_dec[d] + sum_i v_i * WdT[s_i][d]
    float a0 = b_dec[t], a1 = b_dec[t + 256], a2 = b_dec[t + 512];
#pragma unroll 4
    for (int i = 0; i < kk; ++i) {
        float val = win_v[i];
        const float* w = WdT + (long)win_i[i] * DM;
        a0 += val * w[t];
        a1 += val * w[t + 256];
        a2 += val * w[t + 512];
    }
    float* rr = recon + row * DM;
    __builtin_nontemporal_store(a0, rr + t);
    __builtin_nontemporal_store(a1, rr + t + 256);
    __builtin_nontemporal_store(a2, rr + t + 512);
}

// ---------------------------------------------------------------- launch
extern "C" void kernel_launch(void* const* d_in, const int* in_sizes, int n_in,
                              void* d_out, int out_size, void* d_ws, size_t ws_size,
                              hipStream_t stream)
{
    const float* x     = (const float*)d_in[0];
    const float* W_enc = (const float*)d_in[1];
    const float* b_enc = (const float*)d_in[2];
    const float* W_dec = (const float*)d_in[3];
    const float* b_dec = (const float*)d_in[4];
    const int*   kptr  = (const int*)d_in[5];

    const int dmodel = in_sizes[4];               // 768
    const int dsae   = in_sizes[2];               // 12288
    const int M      = in_sizes[0] / dmodel;      // 8192

    float* recon  = (float*)d_out;                          // [M][DM]
    float* sparse = (float*)d_out + (size_t)M * dmodel;     // [M][DS]

    char* ws = (char*)d_ws;
    _Float16* xh  = (_Float16*)ws;          ws += (size_t)M * dmodel * 2;
    _Float16* wh  = (_Float16*)ws;          ws += (size_t)dsae * dmodel * 2;
    float*    WdT = (float*)ws;             ws += (size_t)dsae * dmodel * 4;
    unsigned long long* cand = (unsigned long long*)ws; ws += (size_t)M * CAP * 8;
    unsigned* cnt = (unsigned*)ws;          ws += (size_t)M * 4;
    float*    tau = (float*)ws;             ws += (size_t)M * 4;

    const int n4w = dsae * dmodel / 4;
    k_prep<<<M, 64, 0, stream>>>(x, xh, tau, cnt);
    k_split1<<<(n4w + 255) / 256, 256, 0, stream>>>(W_enc, wh, n4w, 256.0f);
    k_transpose<<<dim3(dsae / 32, dmodel / 32), 256, 0, stream>>>(W_dec, WdT);
    k_encode<<<(M / 128) * (dsae / 128), 256, 0, stream>>>(xh, wh, b_enc, tau, cnt, cand);
    k_select_decode<<<M, 256, 0, stream>>>(cand, cnt, tau, sparse, recon, WdT, b_dec,
                                           kptr, x, W_enc, b_enc);
}